// Round 1
// baseline (856.499 us; speedup 1.0000x reference)
//
#include <hip/hip_runtime.h>

#define N_TILE 50000
#define N_RR   50000
#define D      128
#define E_TT   800000
#define E_RT   400000
#define E_TR   400000
#define N_G    16

// ---------------- histogram (degrees) ----------------
__global__ void k_hist(const int* __restrict__ src, const int* __restrict__ dst,
                       int* __restrict__ odeg, int* __restrict__ ideg, int E) {
  int i = blockIdx.x * blockDim.x + threadIdx.x;
  int stride = gridDim.x * blockDim.x;
  for (; i < E; i += stride) {
    atomicAdd(&odeg[src[i]], 1);
    atomicAdd(&ideg[dst[i]], 1);
  }
}

// ---------------- exclusive scan of 3 degree arrays (one block each) ----------------
__global__ __launch_bounds__(1024) void k_scan(const int* __restrict__ d0, int* __restrict__ r0,
                                               const int* __restrict__ d1, int* __restrict__ r1,
                                               const int* __restrict__ d2, int* __restrict__ r2,
                                               int n) {
  const int* deg = blockIdx.x == 0 ? d0 : (blockIdx.x == 1 ? d1 : d2);
  int* rp = blockIdx.x == 0 ? r0 : (blockIdx.x == 1 ? r1 : r2);
  __shared__ int ts[1024];
  int tid = threadIdx.x;
  int chunk = (n + 1023) / 1024;
  int lo = tid * chunk, hi = min(lo + chunk, n);
  int s = 0;
  for (int i = lo; i < hi; ++i) s += deg[i];
  ts[tid] = s;
  __syncthreads();
  for (int d = 1; d < 1024; d <<= 1) {
    int v = (tid >= d) ? ts[tid - d] : 0;
    __syncthreads();
    ts[tid] += v;
    __syncthreads();
  }
  int off = ts[tid] - s;   // exclusive prefix of my chunk
  for (int i = lo; i < hi; ++i) { rp[i] = off; off += deg[i]; }
  if (tid == 1023) rp[n] = ts[1023];
}

// ---------------- fill CSR (dst-sorted) ----------------
__global__ void k_fill(const int* __restrict__ src, const int* __restrict__ dst,
                       const int* __restrict__ rp, int* __restrict__ cur,
                       int* __restrict__ csr, int E) {
  int i = blockIdx.x * blockDim.x + threadIdx.x;
  int stride = gridDim.x * blockDim.x;
  for (; i < E; i += stride) {
    int d = dst[i];
    int p = atomicAdd(&cur[d], 1);
    csr[rp[d] + p] = src[i];
  }
}

// ---------------- degree -> scale ----------------
__global__ void k_scales(const int* __restrict__ od0, const int* __restrict__ id0,
                         const int* __restrict__ od1, const int* __restrict__ id1,
                         const int* __restrict__ od2, const int* __restrict__ id2,
                         float* __restrict__ os0, float* __restrict__ is0,
                         float* __restrict__ os1, float* __restrict__ is1,
                         float* __restrict__ os2, float* __restrict__ is2, int n) {
  int i = blockIdx.x * blockDim.x + threadIdx.x;
  if (i >= n) return;
  os0[i] = rsqrtf((float)max(od0[i], 1));
  is0[i] = rsqrtf((float)max(id0[i], 1));
  os1[i] = rsqrtf((float)max(od1[i], 1));
  is1[i] = rsqrtf((float)max(id1[i], 1));
  os2[i] = rsqrtf((float)max(od2[i], 1));
  is2[i] = rsqrtf((float)max(id2[i], 1));
}

// ---------------- aggregation: one wave per destination node ----------------
// out[d] = isc[d] * sum_{e in CSR(d)} x[src_e] * osc[src_e]
__global__ __launch_bounds__(256) void k_agg(const float* __restrict__ x,
                                             const int* __restrict__ rp,
                                             const int* __restrict__ csr,
                                             const float* __restrict__ osc,
                                             const float* __restrict__ isc,
                                             float* __restrict__ out, int ndst) {
  int wid = (blockIdx.x * blockDim.x + threadIdx.x) >> 6;
  int lane = threadIdx.x & 63;
  if (wid >= ndst) return;
  int beg = rp[wid], end = rp[wid + 1];
  float ax = 0.f, ay = 0.f;
  for (int e = beg; e < end; ++e) {
    int s = csr[e];
    float sc = osc[s];
    float2 v = *(const float2*)(x + (size_t)s * D + lane * 2);
    ax = fmaf(v.x, sc, ax);
    ay = fmaf(v.y, sc, ay);
  }
  float iv = isc[wid];
  float2 r; r.x = ax * iv; r.y = ay * iv;
  *(float2*)(out + (size_t)wid * D + lane * 2) = r;
}

// ---------------- fused GEMM(+GEMM) + bias + relu ----------------
// out[r][c] = relu( A[r,:]@W1[:,c] (+ B[r,:]@W2[:,c]) + b1[c] (+ b2[c]) )
#define GBM 64
#define GKC 32

template<bool TWO>
__global__ __launch_bounds__(256) void k_gemm(const float* __restrict__ A,
                                              const float* __restrict__ B,
                                              const float* __restrict__ W1,
                                              const float* __restrict__ W2,
                                              const float* __restrict__ b1,
                                              const float* __restrict__ b2,
                                              float* __restrict__ out, int nrows) {
  __shared__ float As[GBM][GKC + 1];   // +1 pad: conflict-free strided reads
  __shared__ float Ws[GKC][132];       // 132 stride: 16B-aligned rows, spread write banks
  int tid = threadIdx.x;
  int tx = tid & 15, ty = tid >> 4;
  int r0 = blockIdx.x * GBM;
  float acc[4][8];
#pragma unroll
  for (int i = 0; i < 4; ++i)
#pragma unroll
    for (int j = 0; j < 8; ++j) acc[i][j] = 0.f;

  const int nrel = TWO ? 2 : 1;
  for (int rel = 0; rel < nrel; ++rel) {
    const float* __restrict__ Xp = (rel == 0) ? A : B;
    const float* __restrict__ Wp = (rel == 0) ? W1 : W2;
    for (int k0 = 0; k0 < D; k0 += GKC) {
      // stage A tile: 64 rows x 32 k
      {
        int lr = tid >> 3;            // 0..31
        int lk = (tid & 7) * 4;       // 0..28
#pragma unroll
        for (int h = 0; h < 2; ++h) {
          int rr = lr + h * 32;
          int gr = r0 + rr;
          float4 v = make_float4(0.f, 0.f, 0.f, 0.f);
          if (gr < nrows) v = *(const float4*)(Xp + (size_t)gr * D + k0 + lk);
          As[rr][lk] = v.x; As[rr][lk + 1] = v.y; As[rr][lk + 2] = v.z; As[rr][lk + 3] = v.w;
        }
        // stage W tile: 32 k x 128 cols
        int wk = tid >> 5;            // 0..7
        int wc = (tid & 31) * 4;      // 0..124
#pragma unroll
        for (int h = 0; h < 4; ++h) {
          int kk = wk + h * 8;
          float4 v = *(const float4*)(Wp + (size_t)(k0 + kk) * D + wc);
          *(float4*)&Ws[kk][wc] = v;
        }
      }
      __syncthreads();
#pragma unroll 8
      for (int k = 0; k < GKC; ++k) {
        float a0 = As[ty * 4 + 0][k];
        float a1 = As[ty * 4 + 1][k];
        float a2 = As[ty * 4 + 2][k];
        float a3 = As[ty * 4 + 3][k];
        float4 bA = *(const float4*)&Ws[k][tx * 4];
        float4 bB = *(const float4*)&Ws[k][64 + tx * 4];
        acc[0][0] = fmaf(a0, bA.x, acc[0][0]); acc[0][1] = fmaf(a0, bA.y, acc[0][1]);
        acc[0][2] = fmaf(a0, bA.z, acc[0][2]); acc[0][3] = fmaf(a0, bA.w, acc[0][3]);
        acc[0][4] = fmaf(a0, bB.x, acc[0][4]); acc[0][5] = fmaf(a0, bB.y, acc[0][5]);
        acc[0][6] = fmaf(a0, bB.z, acc[0][6]); acc[0][7] = fmaf(a0, bB.w, acc[0][7]);
        acc[1][0] = fmaf(a1, bA.x, acc[1][0]); acc[1][1] = fmaf(a1, bA.y, acc[1][1]);
        acc[1][2] = fmaf(a1, bA.z, acc[1][2]); acc[1][3] = fmaf(a1, bA.w, acc[1][3]);
        acc[1][4] = fmaf(a1, bB.x, acc[1][4]); acc[1][5] = fmaf(a1, bB.y, acc[1][5]);
        acc[1][6] = fmaf(a1, bB.z, acc[1][6]); acc[1][7] = fmaf(a1, bB.w, acc[1][7]);
        acc[2][0] = fmaf(a2, bA.x, acc[2][0]); acc[2][1] = fmaf(a2, bA.y, acc[2][1]);
        acc[2][2] = fmaf(a2, bA.z, acc[2][2]); acc[2][3] = fmaf(a2, bA.w, acc[2][3]);
        acc[2][4] = fmaf(a2, bB.x, acc[2][4]); acc[2][5] = fmaf(a2, bB.y, acc[2][5]);
        acc[2][6] = fmaf(a2, bB.z, acc[2][6]); acc[2][7] = fmaf(a2, bB.w, acc[2][7]);
        acc[3][0] = fmaf(a3, bA.x, acc[3][0]); acc[3][1] = fmaf(a3, bA.y, acc[3][1]);
        acc[3][2] = fmaf(a3, bA.z, acc[3][2]); acc[3][3] = fmaf(a3, bA.w, acc[3][3]);
        acc[3][4] = fmaf(a3, bB.x, acc[3][4]); acc[3][5] = fmaf(a3, bB.y, acc[3][5]);
        acc[3][6] = fmaf(a3, bB.z, acc[3][6]); acc[3][7] = fmaf(a3, bB.w, acc[3][7]);
      }
      __syncthreads();
    }
  }

  // epilogue: bias + relu + store
  float4 c0 = *(const float4*)&b1[tx * 4];
  float4 c1 = *(const float4*)&b1[64 + tx * 4];
  if constexpr (TWO) {
    float4 d0 = *(const float4*)&b2[tx * 4];
    float4 d1 = *(const float4*)&b2[64 + tx * 4];
    c0.x += d0.x; c0.y += d0.y; c0.z += d0.z; c0.w += d0.w;
    c1.x += d1.x; c1.y += d1.y; c1.z += d1.z; c1.w += d1.w;
  }
#pragma unroll
  for (int i = 0; i < 4; ++i) {
    int gr = r0 + ty * 4 + i;
    if (gr < nrows) {
      float4 o0, o1;
      o0.x = fmaxf(acc[i][0] + c0.x, 0.f);
      o0.y = fmaxf(acc[i][1] + c0.y, 0.f);
      o0.z = fmaxf(acc[i][2] + c0.z, 0.f);
      o0.w = fmaxf(acc[i][3] + c0.w, 0.f);
      o1.x = fmaxf(acc[i][4] + c1.x, 0.f);
      o1.y = fmaxf(acc[i][5] + c1.y, 0.f);
      o1.z = fmaxf(acc[i][6] + c1.z, 0.f);
      o1.w = fmaxf(acc[i][7] + c1.w, 0.f);
      *(float4*)(out + (size_t)gr * D + tx * 4) = o0;
      *(float4*)(out + (size_t)gr * D + 64 + tx * 4) = o1;
    }
  }
}

// ---------------- per-graph mean pooling (sorted gid -> segment partials) ----------------
#define PCHUNK 256
__global__ __launch_bounds__(128) void k_pool(const float* __restrict__ H,
                                              const int* __restrict__ gid,
                                              float* __restrict__ sums,
                                              float* __restrict__ cnt, int n) {
  int col = threadIdx.x;
  int start = blockIdx.x * PCHUNK;
  if (start >= n) return;
  int end = min(start + PCHUNK, n);
  float acc = 0.f;
  int cur = gid[start];
  int seglen = 0;
  for (int r = start; r < end; ++r) {
    int g = gid[r];
    if (g != cur) {
      atomicAdd(&sums[cur * D + col], acc);
      if (col == 0) atomicAdd(&cnt[cur], (float)seglen);
      acc = 0.f; seglen = 0; cur = g;
    }
    acc += H[(size_t)r * D + col];
    seglen++;
  }
  atomicAdd(&sums[cur * D + col], acc);
  if (col == 0) atomicAdd(&cnt[cur], (float)seglen);
}

// ---------------- final MLP on [16,128] ----------------
__global__ __launch_bounds__(256) void k_final(const float* __restrict__ sums,
                                               const float* __restrict__ cnt,
                                               const float* __restrict__ Wm1,
                                               const float* __restrict__ bm1,
                                               const float* __restrict__ Wm2,
                                               const float* __restrict__ bm2,
                                               float* __restrict__ out) {
  __shared__ float hg[16][128];
  __shared__ float t1[16][128];
  int tid = threadIdx.x;
  for (int i = tid; i < 16 * 128; i += 256) {
    int g = i >> 7, c = i & 127;
    hg[g][c] = sums[i] / fmaxf(cnt[g], 1.f);
  }
  __syncthreads();
  for (int i = tid; i < 16 * 128; i += 256) {
    int g = i >> 7, c = i & 127;
    float a = bm1[c];
    for (int k = 0; k < 128; ++k) a = fmaf(hg[g][k], Wm1[k * 128 + c], a);
    t1[g][c] = fmaxf(a, 0.f);
  }
  __syncthreads();
  int g = tid >> 4, l = tid & 15;
  float p = 0.f;
  for (int c = l; c < 128; c += 16) p = fmaf(t1[g][c], Wm2[c], p);
#pragma unroll
  for (int o = 8; o; o >>= 1) p += __shfl_down(p, o, 16);
  if (l == 0) out[g] = p + bm2[0];
}

extern "C" void kernel_launch(void* const* d_in, const int* in_sizes, int n_in,
                              void* d_out, int out_size, void* d_ws, size_t ws_size,
                              hipStream_t stream) {
  const float* x_tile = (const float*)d_in[0];
  const float* x_rr   = (const float*)d_in[1];
  const int* tt_src = (const int*)d_in[2];
  const int* tt_dst = (const int*)d_in[3];
  const int* rt_src = (const int*)d_in[4];
  const int* rt_dst = (const int*)d_in[5];
  const int* tr_src = (const int*)d_in[6];
  const int* tr_dst = (const int*)d_in[7];
  const int* tile_gid = (const int*)d_in[8];
  const float* W1_tt = (const float*)d_in[9];  const float* b1_tt = (const float*)d_in[10];
  const float* W1_rt = (const float*)d_in[11]; const float* b1_rt = (const float*)d_in[12];
  const float* W1_tr = (const float*)d_in[13]; const float* b1_tr = (const float*)d_in[14];
  const float* W2_tt = (const float*)d_in[15]; const float* b2_tt = (const float*)d_in[16];
  const float* W2_rt = (const float*)d_in[17]; const float* b2_rt = (const float*)d_in[18];
  const float* Wm1 = (const float*)d_in[21]; const float* bm1 = (const float*)d_in[22];
  const float* Wm2 = (const float*)d_in[23]; const float* bm2 = (const float*)d_in[24];

  char* ws = (char*)d_ws;
  size_t off = 0;
  auto alloc = [&](size_t elems) {
    void* p = ws + off;
    off += (elems * 4 + 255) & ~(size_t)255;
    return p;
  };
  // ---- zero region (memset each call) ----
  int* ideg_tt = (int*)alloc(N_TILE);
  int* odeg_tt = (int*)alloc(N_TILE);
  int* ideg_rt = (int*)alloc(N_TILE);
  int* odeg_rt = (int*)alloc(N_RR);
  int* ideg_tr = (int*)alloc(N_RR);
  int* odeg_tr = (int*)alloc(N_TILE);
  int* cur_tt = (int*)alloc(N_TILE);
  int* cur_rt = (int*)alloc(N_TILE);
  int* cur_tr = (int*)alloc(N_RR);
  float* psum = (float*)alloc(N_G * D);
  float* pcnt = (float*)alloc(N_G);
  size_t zero_bytes = off;
  // ---- rest ----
  int* rp_tt = (int*)alloc(N_TILE + 1);
  int* rp_rt = (int*)alloc(N_TILE + 1);
  int* rp_tr = (int*)alloc(N_RR + 1);
  int* csr_tt = (int*)alloc(E_TT);
  int* csr_rt = (int*)alloc(E_RT);
  int* csr_tr = (int*)alloc(E_TR);
  float* osc_tt = (float*)alloc(N_TILE);
  float* isc_tt = (float*)alloc(N_TILE);
  float* osc_rt = (float*)alloc(N_RR);
  float* isc_rt = (float*)alloc(N_TILE);
  float* osc_tr = (float*)alloc(N_TILE);
  float* isc_tr = (float*)alloc(N_RR);
  float* Abuf = (float*)alloc((size_t)N_TILE * D);
  float* Bbuf = (float*)alloc((size_t)N_TILE * D);
  float* Htile = (float*)alloc((size_t)N_TILE * D);
  float* Hrr = (float*)alloc((size_t)N_RR * D);
  (void)ws_size; (void)in_sizes; (void)n_in; (void)out_size;

  hipMemsetAsync(d_ws, 0, zero_bytes, stream);

  // ---- CSR build (edges identical for both layers -> build once) ----
  k_hist<<<2048, 256, 0, stream>>>(tt_src, tt_dst, odeg_tt, ideg_tt, E_TT);
  k_hist<<<1024, 256, 0, stream>>>(rt_src, rt_dst, odeg_rt, ideg_rt, E_RT);
  k_hist<<<1024, 256, 0, stream>>>(tr_src, tr_dst, odeg_tr, ideg_tr, E_TR);
  k_scan<<<3, 1024, 0, stream>>>(ideg_tt, rp_tt, ideg_rt, rp_rt, ideg_tr, rp_tr, N_TILE);
  k_fill<<<2048, 256, 0, stream>>>(tt_src, tt_dst, rp_tt, cur_tt, csr_tt, E_TT);
  k_fill<<<1024, 256, 0, stream>>>(rt_src, rt_dst, rp_rt, cur_rt, csr_rt, E_RT);
  k_fill<<<1024, 256, 0, stream>>>(tr_src, tr_dst, rp_tr, cur_tr, csr_tr, E_TR);
  k_scales<<<(N_TILE + 255) / 256, 256, 0, stream>>>(
      odeg_tt, ideg_tt, odeg_rt, ideg_rt, odeg_tr, ideg_tr,
      osc_tt, isc_tt, osc_rt, isc_rt, osc_tr, isc_tr, N_TILE);

  const int aggBlocks = (N_TILE * 64 + 255) / 256;
  const int gemmBlocks = (N_TILE + GBM - 1) / GBM;

  // ---- layer 1 ----
  k_agg<<<aggBlocks, 256, 0, stream>>>(x_tile, rp_tt, csr_tt, osc_tt, isc_tt, Abuf, N_TILE);
  k_agg<<<aggBlocks, 256, 0, stream>>>(x_rr,  rp_rt, csr_rt, osc_rt, isc_rt, Bbuf, N_TILE);
  k_gemm<true><<<gemmBlocks, 256, 0, stream>>>(Abuf, Bbuf, W1_tt, W1_rt, b1_tt, b1_rt, Htile, N_TILE);
  k_agg<<<aggBlocks, 256, 0, stream>>>(x_tile, rp_tr, csr_tr, osc_tr, isc_tr, Abuf, N_RR);
  k_gemm<false><<<gemmBlocks, 256, 0, stream>>>(Abuf, nullptr, W1_tr, nullptr, b1_tr, nullptr, Hrr, N_RR);

  // ---- layer 2 (h2_rr is never consumed -> tr relation skipped entirely) ----
  k_agg<<<aggBlocks, 256, 0, stream>>>(Htile, rp_tt, csr_tt, osc_tt, isc_tt, Abuf, N_TILE);
  k_agg<<<aggBlocks, 256, 0, stream>>>(Hrr,   rp_rt, csr_rt, osc_rt, isc_rt, Bbuf, N_TILE);
  k_gemm<true><<<gemmBlocks, 256, 0, stream>>>(Abuf, Bbuf, W2_tt, W2_rt, b2_tt, b2_rt, Htile, N_TILE);

  // ---- pooling + MLP head ----
  k_pool<<<(N_TILE + PCHUNK - 1) / PCHUNK, 128, 0, stream>>>(Htile, tile_gid, psum, pcnt, N_TILE);
  k_final<<<1, 256, 0, stream>>>(psum, pcnt, Wm1, bm1, Wm2, bm2, (float*)d_out);
}

// Round 2
// 759.212 us; speedup vs baseline: 1.1281x; 1.1281x over previous
//
#include <hip/hip_runtime.h>

#define N_TILE 50000
#define N_RR   50000
#define D      128
#define E_TT   800000
#define E_RT   400000
#define E_TR   400000
#define N_G    16

// ---------------- histogram (degrees) ----------------
__global__ void k_hist(const int* __restrict__ src, const int* __restrict__ dst,
                       int* __restrict__ odeg, int* __restrict__ ideg, int E) {
  int i = blockIdx.x * blockDim.x + threadIdx.x;
  int stride = gridDim.x * blockDim.x;
  for (; i < E; i += stride) {
    atomicAdd(&odeg[src[i]], 1);
    atomicAdd(&ideg[dst[i]], 1);
  }
}

// ---------------- exclusive scan of 3 degree arrays (one block each) ----------------
__global__ __launch_bounds__(1024) void k_scan(const int* __restrict__ d0, int* __restrict__ r0,
                                               const int* __restrict__ d1, int* __restrict__ r1,
                                               const int* __restrict__ d2, int* __restrict__ r2,
                                               int n) {
  const int* deg = blockIdx.x == 0 ? d0 : (blockIdx.x == 1 ? d1 : d2);
  int* rp = blockIdx.x == 0 ? r0 : (blockIdx.x == 1 ? r1 : r2);
  __shared__ int ts[1024];
  int tid = threadIdx.x;
  int chunk = (n + 1023) / 1024;
  int lo = tid * chunk, hi = min(lo + chunk, n);
  int s = 0;
  for (int i = lo; i < hi; ++i) s += deg[i];
  ts[tid] = s;
  __syncthreads();
  for (int d = 1; d < 1024; d <<= 1) {
    int v = (tid >= d) ? ts[tid - d] : 0;
    __syncthreads();
    ts[tid] += v;
    __syncthreads();
  }
  int off = ts[tid] - s;   // exclusive prefix of my chunk
  for (int i = lo; i < hi; ++i) { rp[i] = off; off += deg[i]; }
  if (tid == 1023) rp[n] = ts[1023];
}

// ---------------- fill CSR (dst-sorted) ----------------
__global__ void k_fill(const int* __restrict__ src, const int* __restrict__ dst,
                       const int* __restrict__ rp, int* __restrict__ cur,
                       int* __restrict__ csr, int E) {
  int i = blockIdx.x * blockDim.x + threadIdx.x;
  int stride = gridDim.x * blockDim.x;
  for (; i < E; i += stride) {
    int d = dst[i];
    int p = atomicAdd(&cur[d], 1);
    csr[rp[d] + p] = src[i];
  }
}

// ---------------- degree -> scale ----------------
__global__ void k_scales(const int* __restrict__ od0, const int* __restrict__ id0,
                         const int* __restrict__ od1, const int* __restrict__ id1,
                         const int* __restrict__ od2, const int* __restrict__ id2,
                         float* __restrict__ os0, float* __restrict__ is0,
                         float* __restrict__ os1, float* __restrict__ is1,
                         float* __restrict__ os2, float* __restrict__ is2, int n) {
  int i = blockIdx.x * blockDim.x + threadIdx.x;
  if (i >= n) return;
  os0[i] = rsqrtf((float)max(od0[i], 1));
  is0[i] = rsqrtf((float)max(id0[i], 1));
  os1[i] = rsqrtf((float)max(od1[i], 1));
  is1[i] = rsqrtf((float)max(id1[i], 1));
  os2[i] = rsqrtf((float)max(od2[i], 1));
  is2[i] = rsqrtf((float)max(id2[i], 1));
}

// ---------------- aggregation: one wave per destination node ----------------
// out[d] = isc[d] * sum_{e in CSR(d)} x[src_e] * osc[src_e]
// 4-way unrolled: 4 independent gather chains in flight per wave.
// Tail is branchless: clamp edge index to end-1, zero the scale.
__global__ __launch_bounds__(256) void k_agg(const float* __restrict__ x,
                                             const int* __restrict__ rp,
                                             const int* __restrict__ csr,
                                             const float* __restrict__ osc,
                                             const float* __restrict__ isc,
                                             float* __restrict__ out, int ndst) {
  int wid = (blockIdx.x * blockDim.x + threadIdx.x) >> 6;
  int lane = threadIdx.x & 63;
  if (wid >= ndst) return;
  int beg = rp[wid], end = rp[wid + 1];
  float ax0 = 0.f, ay0 = 0.f, ax1 = 0.f, ay1 = 0.f;
  float ax2 = 0.f, ay2 = 0.f, ax3 = 0.f, ay3 = 0.f;
  const float* xl = x + lane * 2;
  for (int e = beg; e < end; e += 4) {
    int e1 = min(e + 1, end - 1);
    int e2 = min(e + 2, end - 1);
    int e3 = min(e + 3, end - 1);
    int s0 = csr[e];
    int s1 = csr[e1];
    int s2 = csr[e2];
    int s3 = csr[e3];
    float c0 = osc[s0];
    float c1 = (e + 1 < end) ? osc[s1] : 0.f;
    float c2 = (e + 2 < end) ? osc[s2] : 0.f;
    float c3 = (e + 3 < end) ? osc[s3] : 0.f;
    float2 v0 = *(const float2*)(xl + (size_t)s0 * D);
    float2 v1 = *(const float2*)(xl + (size_t)s1 * D);
    float2 v2 = *(const float2*)(xl + (size_t)s2 * D);
    float2 v3 = *(const float2*)(xl + (size_t)s3 * D);
    ax0 = fmaf(v0.x, c0, ax0); ay0 = fmaf(v0.y, c0, ay0);
    ax1 = fmaf(v1.x, c1, ax1); ay1 = fmaf(v1.y, c1, ay1);
    ax2 = fmaf(v2.x, c2, ax2); ay2 = fmaf(v2.y, c2, ay2);
    ax3 = fmaf(v3.x, c3, ax3); ay3 = fmaf(v3.y, c3, ay3);
  }
  float iv = isc[wid];
  float2 r;
  r.x = ((ax0 + ax1) + (ax2 + ax3)) * iv;
  r.y = ((ay0 + ay1) + (ay2 + ay3)) * iv;
  *(float2*)(out + (size_t)wid * D + lane * 2) = r;
}

// ---------------- fused GEMM(+GEMM) + bias + relu ----------------
// out[r][c] = relu( A[r,:]@W1[:,c] (+ B[r,:]@W2[:,c]) + b1[c] (+ b2[c]) )
#define GBM 64
#define GKC 32

template<bool TWO>
__global__ __launch_bounds__(256) void k_gemm(const float* __restrict__ A,
                                              const float* __restrict__ B,
                                              const float* __restrict__ W1,
                                              const float* __restrict__ W2,
                                              const float* __restrict__ b1,
                                              const float* __restrict__ b2,
                                              float* __restrict__ out, int nrows) {
  __shared__ float As[GBM][GKC + 1];   // +1 pad: conflict-free strided reads
  __shared__ float Ws[GKC][132];       // 132 stride: 16B-aligned rows, spread write banks
  int tid = threadIdx.x;
  int tx = tid & 15, ty = tid >> 4;
  int r0 = blockIdx.x * GBM;
  float acc[4][8];
#pragma unroll
  for (int i = 0; i < 4; ++i)
#pragma unroll
    for (int j = 0; j < 8; ++j) acc[i][j] = 0.f;

  const int nrel = TWO ? 2 : 1;
  for (int rel = 0; rel < nrel; ++rel) {
    const float* __restrict__ Xp = (rel == 0) ? A : B;
    const float* __restrict__ Wp = (rel == 0) ? W1 : W2;
    for (int k0 = 0; k0 < D; k0 += GKC) {
      // stage A tile: 64 rows x 32 k
      {
        int lr = tid >> 3;            // 0..31
        int lk = (tid & 7) * 4;       // 0..28
#pragma unroll
        for (int h = 0; h < 2; ++h) {
          int rr = lr + h * 32;
          int gr = r0 + rr;
          float4 v = make_float4(0.f, 0.f, 0.f, 0.f);
          if (gr < nrows) v = *(const float4*)(Xp + (size_t)gr * D + k0 + lk);
          As[rr][lk] = v.x; As[rr][lk + 1] = v.y; As[rr][lk + 2] = v.z; As[rr][lk + 3] = v.w;
        }
        // stage W tile: 32 k x 128 cols
        int wk = tid >> 5;            // 0..7
        int wc = (tid & 31) * 4;      // 0..124
#pragma unroll
        for (int h = 0; h < 4; ++h) {
          int kk = wk + h * 8;
          float4 v = *(const float4*)(Wp + (size_t)(k0 + kk) * D + wc);
          *(float4*)&Ws[kk][wc] = v;
        }
      }
      __syncthreads();
#pragma unroll 8
      for (int k = 0; k < GKC; ++k) {
        float a0 = As[ty * 4 + 0][k];
        float a1 = As[ty * 4 + 1][k];
        float a2 = As[ty * 4 + 2][k];
        float a3 = As[ty * 4 + 3][k];
        float4 bA = *(const float4*)&Ws[k][tx * 4];
        float4 bB = *(const float4*)&Ws[k][64 + tx * 4];
        acc[0][0] = fmaf(a0, bA.x, acc[0][0]); acc[0][1] = fmaf(a0, bA.y, acc[0][1]);
        acc[0][2] = fmaf(a0, bA.z, acc[0][2]); acc[0][3] = fmaf(a0, bA.w, acc[0][3]);
        acc[0][4] = fmaf(a0, bB.x, acc[0][4]); acc[0][5] = fmaf(a0, bB.y, acc[0][5]);
        acc[0][6] = fmaf(a0, bB.z, acc[0][6]); acc[0][7] = fmaf(a0, bB.w, acc[0][7]);
        acc[1][0] = fmaf(a1, bA.x, acc[1][0]); acc[1][1] = fmaf(a1, bA.y, acc[1][1]);
        acc[1][2] = fmaf(a1, bA.z, acc[1][2]); acc[1][3] = fmaf(a1, bA.w, acc[1][3]);
        acc[1][4] = fmaf(a1, bB.x, acc[1][4]); acc[1][5] = fmaf(a1, bB.y, acc[1][5]);
        acc[1][6] = fmaf(a1, bB.z, acc[1][6]); acc[1][7] = fmaf(a1, bB.w, acc[1][7]);
        acc[2][0] = fmaf(a2, bA.x, acc[2][0]); acc[2][1] = fmaf(a2, bA.y, acc[2][1]);
        acc[2][2] = fmaf(a2, bA.z, acc[2][2]); acc[2][3] = fmaf(a2, bA.w, acc[2][3]);
        acc[2][4] = fmaf(a2, bB.x, acc[2][4]); acc[2][5] = fmaf(a2, bB.y, acc[2][5]);
        acc[2][6] = fmaf(a2, bB.z, acc[2][6]); acc[2][7] = fmaf(a2, bB.w, acc[2][7]);
        acc[3][0] = fmaf(a3, bA.x, acc[3][0]); acc[3][1] = fmaf(a3, bA.y, acc[3][1]);
        acc[3][2] = fmaf(a3, bA.z, acc[3][2]); acc[3][3] = fmaf(a3, bA.w, acc[3][3]);
        acc[3][4] = fmaf(a3, bB.x, acc[3][4]); acc[3][5] = fmaf(a3, bB.y, acc[3][5]);
        acc[3][6] = fmaf(a3, bB.z, acc[3][6]); acc[3][7] = fmaf(a3, bB.w, acc[3][7]);
      }
      __syncthreads();
    }
  }

  // epilogue: bias + relu + store
  float4 c0 = *(const float4*)&b1[tx * 4];
  float4 c1 = *(const float4*)&b1[64 + tx * 4];
  if constexpr (TWO) {
    float4 d0 = *(const float4*)&b2[tx * 4];
    float4 d1 = *(const float4*)&b2[64 + tx * 4];
    c0.x += d0.x; c0.y += d0.y; c0.z += d0.z; c0.w += d0.w;
    c1.x += d1.x; c1.y += d1.y; c1.z += d1.z; c1.w += d1.w;
  }
#pragma unroll
  for (int i = 0; i < 4; ++i) {
    int gr = r0 + ty * 4 + i;
    if (gr < nrows) {
      float4 o0, o1;
      o0.x = fmaxf(acc[i][0] + c0.x, 0.f);
      o0.y = fmaxf(acc[i][1] + c0.y, 0.f);
      o0.z = fmaxf(acc[i][2] + c0.z, 0.f);
      o0.w = fmaxf(acc[i][3] + c0.w, 0.f);
      o1.x = fmaxf(acc[i][4] + c1.x, 0.f);
      o1.y = fmaxf(acc[i][5] + c1.y, 0.f);
      o1.z = fmaxf(acc[i][6] + c1.z, 0.f);
      o1.w = fmaxf(acc[i][7] + c1.w, 0.f);
      *(float4*)(out + (size_t)gr * D + tx * 4) = o0;
      *(float4*)(out + (size_t)gr * D + 64 + tx * 4) = o1;
    }
  }
}

// ---------------- per-graph mean pooling (sorted gid -> segment partials) ----------------
#define PCHUNK 256
__global__ __launch_bounds__(128) void k_pool(const float* __restrict__ H,
                                              const int* __restrict__ gid,
                                              float* __restrict__ sums,
                                              float* __restrict__ cnt, int n) {
  int col = threadIdx.x;
  int start = blockIdx.x * PCHUNK;
  if (start >= n) return;
  int end = min(start + PCHUNK, n);
  float acc = 0.f;
  int cur = gid[start];
  int seglen = 0;
  for (int r = start; r < end; ++r) {
    int g = gid[r];
    if (g != cur) {
      atomicAdd(&sums[cur * D + col], acc);
      if (col == 0) atomicAdd(&cnt[cur], (float)seglen);
      acc = 0.f; seglen = 0; cur = g;
    }
    acc += H[(size_t)r * D + col];
    seglen++;
  }
  atomicAdd(&sums[cur * D + col], acc);
  if (col == 0) atomicAdd(&cnt[cur], (float)seglen);
}

// ---------------- final MLP on [16,128] ----------------
__global__ __launch_bounds__(256) void k_final(const float* __restrict__ sums,
                                               const float* __restrict__ cnt,
                                               const float* __restrict__ Wm1,
                                               const float* __restrict__ bm1,
                                               const float* __restrict__ Wm2,
                                               const float* __restrict__ bm2,
                                               float* __restrict__ out) {
  __shared__ float hg[16][128];
  __shared__ float t1[16][128];
  int tid = threadIdx.x;
  for (int i = tid; i < 16 * 128; i += 256) {
    int g = i >> 7, c = i & 127;
    hg[g][c] = sums[i] / fmaxf(cnt[g], 1.f);
  }
  __syncthreads();
  for (int i = tid; i < 16 * 128; i += 256) {
    int g = i >> 7, c = i & 127;
    float a = bm1[c];
    for (int k = 0; k < 128; ++k) a = fmaf(hg[g][k], Wm1[k * 128 + c], a);
    t1[g][c] = fmaxf(a, 0.f);
  }
  __syncthreads();
  int g = tid >> 4, l = tid & 15;
  float p = 0.f;
  for (int c = l; c < 128; c += 16) p = fmaf(t1[g][c], Wm2[c], p);
#pragma unroll
  for (int o = 8; o; o >>= 1) p += __shfl_down(p, o, 16);
  if (l == 0) out[g] = p + bm2[0];
}

extern "C" void kernel_launch(void* const* d_in, const int* in_sizes, int n_in,
                              void* d_out, int out_size, void* d_ws, size_t ws_size,
                              hipStream_t stream) {
  const float* x_tile = (const float*)d_in[0];
  const float* x_rr   = (const float*)d_in[1];
  const int* tt_src = (const int*)d_in[2];
  const int* tt_dst = (const int*)d_in[3];
  const int* rt_src = (const int*)d_in[4];
  const int* rt_dst = (const int*)d_in[5];
  const int* tr_src = (const int*)d_in[6];
  const int* tr_dst = (const int*)d_in[7];
  const int* tile_gid = (const int*)d_in[8];
  const float* W1_tt = (const float*)d_in[9];  const float* b1_tt = (const float*)d_in[10];
  const float* W1_rt = (const float*)d_in[11]; const float* b1_rt = (const float*)d_in[12];
  const float* W1_tr = (const float*)d_in[13]; const float* b1_tr = (const float*)d_in[14];
  const float* W2_tt = (const float*)d_in[15]; const float* b2_tt = (const float*)d_in[16];
  const float* W2_rt = (const float*)d_in[17]; const float* b2_rt = (const float*)d_in[18];
  const float* Wm1 = (const float*)d_in[21]; const float* bm1 = (const float*)d_in[22];
  const float* Wm2 = (const float*)d_in[23]; const float* bm2 = (const float*)d_in[24];

  char* ws = (char*)d_ws;
  size_t off = 0;
  auto alloc = [&](size_t elems) {
    void* p = ws + off;
    off += (elems * 4 + 255) & ~(size_t)255;
    return p;
  };
  // ---- zero region (memset each call) ----
  int* ideg_tt = (int*)alloc(N_TILE);
  int* odeg_tt = (int*)alloc(N_TILE);
  int* ideg_rt = (int*)alloc(N_TILE);
  int* odeg_rt = (int*)alloc(N_RR);
  int* ideg_tr = (int*)alloc(N_RR);
  int* odeg_tr = (int*)alloc(N_TILE);
  int* cur_tt = (int*)alloc(N_TILE);
  int* cur_rt = (int*)alloc(N_TILE);
  int* cur_tr = (int*)alloc(N_RR);
  float* psum = (float*)alloc(N_G * D);
  float* pcnt = (float*)alloc(N_G);
  size_t zero_bytes = off;
  // ---- rest ----
  int* rp_tt = (int*)alloc(N_TILE + 1);
  int* rp_rt = (int*)alloc(N_TILE + 1);
  int* rp_tr = (int*)alloc(N_RR + 1);
  int* csr_tt = (int*)alloc(E_TT);
  int* csr_rt = (int*)alloc(E_RT);
  int* csr_tr = (int*)alloc(E_TR);
  float* osc_tt = (float*)alloc(N_TILE);
  float* isc_tt = (float*)alloc(N_TILE);
  float* osc_rt = (float*)alloc(N_RR);
  float* isc_rt = (float*)alloc(N_TILE);
  float* osc_tr = (float*)alloc(N_TILE);
  float* isc_tr = (float*)alloc(N_RR);
  float* Abuf = (float*)alloc((size_t)N_TILE * D);
  float* Bbuf = (float*)alloc((size_t)N_TILE * D);
  float* Htile = (float*)alloc((size_t)N_TILE * D);
  float* Hrr = (float*)alloc((size_t)N_RR * D);
  (void)ws_size; (void)in_sizes; (void)n_in; (void)out_size;

  hipMemsetAsync(d_ws, 0, zero_bytes, stream);

  // ---- CSR build (edges identical for both layers -> build once) ----
  k_hist<<<2048, 256, 0, stream>>>(tt_src, tt_dst, odeg_tt, ideg_tt, E_TT);
  k_hist<<<1024, 256, 0, stream>>>(rt_src, rt_dst, odeg_rt, ideg_rt, E_RT);
  k_hist<<<1024, 256, 0, stream>>>(tr_src, tr_dst, odeg_tr, ideg_tr, E_TR);
  k_scan<<<3, 1024, 0, stream>>>(ideg_tt, rp_tt, ideg_rt, rp_rt, ideg_tr, rp_tr, N_TILE);
  k_fill<<<2048, 256, 0, stream>>>(tt_src, tt_dst, rp_tt, cur_tt, csr_tt, E_TT);
  k_fill<<<1024, 256, 0, stream>>>(rt_src, rt_dst, rp_rt, cur_rt, csr_rt, E_RT);
  k_fill<<<1024, 256, 0, stream>>>(tr_src, tr_dst, rp_tr, cur_tr, csr_tr, E_TR);
  k_scales<<<(N_TILE + 255) / 256, 256, 0, stream>>>(
      odeg_tt, ideg_tt, odeg_rt, ideg_rt, odeg_tr, ideg_tr,
      osc_tt, isc_tt, osc_rt, isc_rt, osc_tr, isc_tr, N_TILE);

  const int aggBlocks = (N_TILE * 64 + 255) / 256;
  const int gemmBlocks = (N_TILE + GBM - 1) / GBM;

  // ---- layer 1 ----
  k_agg<<<aggBlocks, 256, 0, stream>>>(x_tile, rp_tt, csr_tt, osc_tt, isc_tt, Abuf, N_TILE);
  k_agg<<<aggBlocks, 256, 0, stream>>>(x_rr,  rp_rt, csr_rt, osc_rt, isc_rt, Bbuf, N_TILE);
  k_gemm<true><<<gemmBlocks, 256, 0, stream>>>(Abuf, Bbuf, W1_tt, W1_rt, b1_tt, b1_rt, Htile, N_TILE);
  k_agg<<<aggBlocks, 256, 0, stream>>>(x_tile, rp_tr, csr_tr, osc_tr, isc_tr, Abuf, N_RR);
  k_gemm<false><<<gemmBlocks, 256, 0, stream>>>(Abuf, nullptr, W1_tr, nullptr, b1_tr, nullptr, Hrr, N_RR);

  // ---- layer 2 (h2_rr is never consumed -> tr relation skipped entirely) ----
  k_agg<<<aggBlocks, 256, 0, stream>>>(Htile, rp_tt, csr_tt, osc_tt, isc_tt, Abuf, N_TILE);
  k_agg<<<aggBlocks, 256, 0, stream>>>(Hrr,   rp_rt, csr_rt, osc_rt, isc_rt, Bbuf, N_TILE);
  k_gemm<true><<<gemmBlocks, 256, 0, stream>>>(Abuf, Bbuf, W2_tt, W2_rt, b2_tt, b2_rt, Htile, N_TILE);

  // ---- pooling + MLP head ----
  k_pool<<<(N_TILE + PCHUNK - 1) / PCHUNK, 128, 0, stream>>>(Htile, tile_gid, psum, pcnt, N_TILE);
  k_final<<<1, 256, 0, stream>>>(psum, pcnt, Wm1, bm1, Wm2, bm2, (float*)d_out);
}

// Round 3
// 734.036 us; speedup vs baseline: 1.1668x; 1.0343x over previous
//
#include <hip/hip_runtime.h>

#define N_TILE 50000
#define N_RR   50000
#define D      128
#define E_TT   800000
#define E_RT   400000
#define E_TR   400000
#define N_G    16
#define NB     ((N_TILE + 1023) / 1024)   // scan blocks per array (=49)
#define E_ALL  (E_TT + E_RT + E_TR)

static_assert(NB <= 64, "scan2 uses one wave per array");

// ---------------- fused histogram (degrees, all 3 relations) ----------------
__global__ void k_hist_all(const int* __restrict__ tt_src, const int* __restrict__ tt_dst,
                           const int* __restrict__ rt_src, const int* __restrict__ rt_dst,
                           const int* __restrict__ tr_src, const int* __restrict__ tr_dst,
                           int* __restrict__ od_tt, int* __restrict__ id_tt,
                           int* __restrict__ od_rt, int* __restrict__ id_rt,
                           int* __restrict__ od_tr, int* __restrict__ id_tr) {
  int i = blockIdx.x * blockDim.x + threadIdx.x;
  if (i >= E_ALL) return;
  if (i < E_TT) {
    atomicAdd(&od_tt[tt_src[i]], 1);
    atomicAdd(&id_tt[tt_dst[i]], 1);
  } else if (i < E_TT + E_RT) {
    int j = i - E_TT;
    atomicAdd(&od_rt[rt_src[j]], 1);
    atomicAdd(&id_rt[rt_dst[j]], 1);
  } else {
    int j = i - E_TT - E_RT;
    atomicAdd(&od_tr[tr_src[j]], 1);
    atomicAdd(&id_tr[tr_dst[j]], 1);
  }
}

// ---------------- scan stage 1: per-block exclusive scan (1024 elems/block) ----------------
__global__ __launch_bounds__(1024) void k_scan1(const int* __restrict__ d0,
                                                const int* __restrict__ d1,
                                                const int* __restrict__ d2,
                                                int* __restrict__ p0,
                                                int* __restrict__ p1,
                                                int* __restrict__ p2,
                                                int* __restrict__ bsum) {
  int arr = blockIdx.x / NB;
  int blk = blockIdx.x % NB;
  const int* deg = arr == 0 ? d0 : (arr == 1 ? d1 : d2);
  int* part = arr == 0 ? p0 : (arr == 1 ? p1 : p2);
  __shared__ int ts[1024];
  int tid = threadIdx.x;
  int i = blk * 1024 + tid;
  int v = (i < N_TILE) ? deg[i] : 0;
  ts[tid] = v;
  __syncthreads();
  for (int d = 1; d < 1024; d <<= 1) {
    int t = (tid >= d) ? ts[tid - d] : 0;
    __syncthreads();
    ts[tid] += t;
    __syncthreads();
  }
  if (i < N_TILE) part[i] = ts[tid] - v;   // exclusive within block
  if (tid == 1023) bsum[arr * NB + blk] = ts[1023];
}

// ---------------- scan stage 2: scan the block sums (1 wave / array) ----------------
__global__ __launch_bounds__(256) void k_scan2(const int* __restrict__ bsum,
                                               int* __restrict__ bs) {
  int wv = threadIdx.x >> 6;
  int lane = threadIdx.x & 63;
  if (wv >= 3) return;
  int v = (lane < NB) ? bsum[wv * NB + lane] : 0;
  int orig = v;
#pragma unroll
  for (int o = 1; o < 64; o <<= 1) {
    int t = __shfl_up(v, o);
    if (lane >= o) v += t;
  }
  if (lane < NB) bs[wv * (NB + 1) + lane] = v - orig;   // exclusive
  if (lane == NB - 1) bs[wv * (NB + 1) + NB] = v;       // total
}

// ---------------- finalize: rp = part + block offset; degree -> scale ----------------
__global__ void k_finalize(const int* __restrict__ pp_tt, const int* __restrict__ pp_rt,
                           const int* __restrict__ pp_tr, const int* __restrict__ bs,
                           int* __restrict__ rp_tt, int* __restrict__ rp_rt,
                           int* __restrict__ rp_tr,
                           const int* __restrict__ od_tt, const int* __restrict__ id_tt,
                           const int* __restrict__ od_rt, const int* __restrict__ id_rt,
                           const int* __restrict__ od_tr, const int* __restrict__ id_tr,
                           float* __restrict__ os_tt, float* __restrict__ is_tt,
                           float* __restrict__ os_rt, float* __restrict__ is_rt,
                           float* __restrict__ os_tr, float* __restrict__ is_tr) {
  int i = blockIdx.x * blockDim.x + threadIdx.x;
  if (i >= N_TILE) return;
  int b = i >> 10;
  rp_tt[i] = pp_tt[i] + bs[0 * (NB + 1) + b];
  rp_rt[i] = pp_rt[i] + bs[1 * (NB + 1) + b];
  rp_tr[i] = pp_tr[i] + bs[2 * (NB + 1) + b];
  if (i == 0) {
    rp_tt[N_TILE] = bs[0 * (NB + 1) + NB];
    rp_rt[N_TILE] = bs[1 * (NB + 1) + NB];
    rp_tr[N_RR] = bs[2 * (NB + 1) + NB];
  }
  os_tt[i] = rsqrtf((float)max(od_tt[i], 1));
  is_tt[i] = rsqrtf((float)max(id_tt[i], 1));
  os_rt[i] = rsqrtf((float)max(od_rt[i], 1));
  is_rt[i] = rsqrtf((float)max(id_rt[i], 1));
  os_tr[i] = rsqrtf((float)max(od_tr[i], 1));
  is_tr[i] = rsqrtf((float)max(id_tr[i], 1));
}

// ---------------- fused CSR fill (all 3 relations) ----------------
__global__ void k_fill_all(const int* __restrict__ tt_src, const int* __restrict__ tt_dst,
                           const int* __restrict__ rt_src, const int* __restrict__ rt_dst,
                           const int* __restrict__ tr_src, const int* __restrict__ tr_dst,
                           const int* __restrict__ rp_tt, const int* __restrict__ rp_rt,
                           const int* __restrict__ rp_tr,
                           int* __restrict__ cur_tt, int* __restrict__ cur_rt,
                           int* __restrict__ cur_tr,
                           int* __restrict__ csr_tt, int* __restrict__ csr_rt,
                           int* __restrict__ csr_tr) {
  int i = blockIdx.x * blockDim.x + threadIdx.x;
  if (i >= E_ALL) return;
  const int* src; const int* dst; const int* rp; int* cur; int* csr; int j;
  if (i < E_TT) { j = i; src = tt_src; dst = tt_dst; rp = rp_tt; cur = cur_tt; csr = csr_tt; }
  else if (i < E_TT + E_RT) { j = i - E_TT; src = rt_src; dst = rt_dst; rp = rp_rt; cur = cur_rt; csr = csr_rt; }
  else { j = i - E_TT - E_RT; src = tr_src; dst = tr_dst; rp = rp_tr; cur = cur_tr; csr = csr_tr; }
  int d = dst[j];
  int p = atomicAdd(&cur[d], 1);
  csr[rp[d] + p] = src[j];
}

// ---------------- fused aggregation: up to 3 relations, one wave per dst ----------------
// out[d] = isc[d] * sum_{e in CSR(d)} x[src_e] * osc[src_e]
// 8 independent gather chains in flight per wave; branchless tail.
__global__ __launch_bounds__(256) void k_agg3(
    const float* __restrict__ x0, const int* __restrict__ rp0, const int* __restrict__ csr0,
    const float* __restrict__ osc0, const float* __restrict__ isc0, float* __restrict__ out0, int n0,
    const float* __restrict__ x1, const int* __restrict__ rp1, const int* __restrict__ csr1,
    const float* __restrict__ osc1, const float* __restrict__ isc1, float* __restrict__ out1, int n1,
    const float* __restrict__ x2, const int* __restrict__ rp2, const int* __restrict__ csr2,
    const float* __restrict__ osc2, const float* __restrict__ isc2, float* __restrict__ out2, int n2) {
  int gw = (blockIdx.x * blockDim.x + threadIdx.x) >> 6;
  int lane = threadIdx.x & 63;
  const float* x; const int* rp; const int* csr; const float* osc; const float* isc;
  float* out; int wid;
  if (gw < n0) { x = x0; rp = rp0; csr = csr0; osc = osc0; isc = isc0; out = out0; wid = gw; }
  else if (gw < n0 + n1) { x = x1; rp = rp1; csr = csr1; osc = osc1; isc = isc1; out = out1; wid = gw - n0; }
  else if (gw < n0 + n1 + n2) { x = x2; rp = rp2; csr = csr2; osc = osc2; isc = isc2; out = out2; wid = gw - n0 - n1; }
  else return;
  int beg = rp[wid], end = rp[wid + 1];
  float ax[8], ay[8];
#pragma unroll
  for (int u = 0; u < 8; ++u) { ax[u] = 0.f; ay[u] = 0.f; }
  const float* xl = x + lane * 2;
  for (int e = beg; e < end; e += 8) {
    int s[8]; float c[8];
#pragma unroll
    for (int u = 0; u < 8; ++u) {
      int ee = min(e + u, end - 1);
      s[u] = csr[ee];
      c[u] = (e + u < end) ? osc[s[u]] : 0.f;
    }
#pragma unroll
    for (int u = 0; u < 8; ++u) {
      float2 v = *(const float2*)(xl + (size_t)s[u] * D);
      ax[u] = fmaf(v.x, c[u], ax[u]);
      ay[u] = fmaf(v.y, c[u], ay[u]);
    }
  }
  float iv = isc[wid];
  float sx = ((ax[0] + ax[1]) + (ax[2] + ax[3])) + ((ax[4] + ax[5]) + (ax[6] + ax[7]));
  float sy = ((ay[0] + ay[1]) + (ay[2] + ay[3])) + ((ay[4] + ay[5]) + (ay[6] + ay[7]));
  float2 r; r.x = sx * iv; r.y = sy * iv;
  *(float2*)(out + (size_t)wid * D + lane * 2) = r;
}

// ---------------- fused GEMM(+GEMM) + bias + relu ----------------
// out[r][c] = relu( A[r,:]@W1[:,c] (+ B[r,:]@W2[:,c]) + b1[c] (+ b2[c]) )
#define GBM 64
#define GKC 32

template<bool TWO>
__global__ __launch_bounds__(256) void k_gemm(const float* __restrict__ A,
                                              const float* __restrict__ B,
                                              const float* __restrict__ W1,
                                              const float* __restrict__ W2,
                                              const float* __restrict__ b1,
                                              const float* __restrict__ b2,
                                              float* __restrict__ out, int nrows) {
  __shared__ float As[GBM][GKC + 1];
  __shared__ float Ws[GKC][132];
  int tid = threadIdx.x;
  int tx = tid & 15, ty = tid >> 4;
  int r0 = blockIdx.x * GBM;
  float acc[4][8];
#pragma unroll
  for (int i = 0; i < 4; ++i)
#pragma unroll
    for (int j = 0; j < 8; ++j) acc[i][j] = 0.f;

  const int nrel = TWO ? 2 : 1;
  for (int rel = 0; rel < nrel; ++rel) {
    const float* __restrict__ Xp = (rel == 0) ? A : B;
    const float* __restrict__ Wp = (rel == 0) ? W1 : W2;
    for (int k0 = 0; k0 < D; k0 += GKC) {
      {
        int lr = tid >> 3;
        int lk = (tid & 7) * 4;
#pragma unroll
        for (int h = 0; h < 2; ++h) {
          int rr = lr + h * 32;
          int gr = r0 + rr;
          float4 v = make_float4(0.f, 0.f, 0.f, 0.f);
          if (gr < nrows) v = *(const float4*)(Xp + (size_t)gr * D + k0 + lk);
          As[rr][lk] = v.x; As[rr][lk + 1] = v.y; As[rr][lk + 2] = v.z; As[rr][lk + 3] = v.w;
        }
        int wk = tid >> 5;
        int wc = (tid & 31) * 4;
#pragma unroll
        for (int h = 0; h < 4; ++h) {
          int kk = wk + h * 8;
          float4 v = *(const float4*)(Wp + (size_t)(k0 + kk) * D + wc);
          *(float4*)&Ws[kk][wc] = v;
        }
      }
      __syncthreads();
#pragma unroll 8
      for (int k = 0; k < GKC; ++k) {
        float a0 = As[ty * 4 + 0][k];
        float a1 = As[ty * 4 + 1][k];
        float a2 = As[ty * 4 + 2][k];
        float a3 = As[ty * 4 + 3][k];
        float4 bA = *(const float4*)&Ws[k][tx * 4];
        float4 bB = *(const float4*)&Ws[k][64 + tx * 4];
        acc[0][0] = fmaf(a0, bA.x, acc[0][0]); acc[0][1] = fmaf(a0, bA.y, acc[0][1]);
        acc[0][2] = fmaf(a0, bA.z, acc[0][2]); acc[0][3] = fmaf(a0, bA.w, acc[0][3]);
        acc[0][4] = fmaf(a0, bB.x, acc[0][4]); acc[0][5] = fmaf(a0, bB.y, acc[0][5]);
        acc[0][6] = fmaf(a0, bB.z, acc[0][6]); acc[0][7] = fmaf(a0, bB.w, acc[0][7]);
        acc[1][0] = fmaf(a1, bA.x, acc[1][0]); acc[1][1] = fmaf(a1, bA.y, acc[1][1]);
        acc[1][2] = fmaf(a1, bA.z, acc[1][2]); acc[1][3] = fmaf(a1, bA.w, acc[1][3]);
        acc[1][4] = fmaf(a1, bB.x, acc[1][4]); acc[1][5] = fmaf(a1, bB.y, acc[1][5]);
        acc[1][6] = fmaf(a1, bB.z, acc[1][6]); acc[1][7] = fmaf(a1, bB.w, acc[1][7]);
        acc[2][0] = fmaf(a2, bA.x, acc[2][0]); acc[2][1] = fmaf(a2, bA.y, acc[2][1]);
        acc[2][2] = fmaf(a2, bA.z, acc[2][2]); acc[2][3] = fmaf(a2, bA.w, acc[2][3]);
        acc[2][4] = fmaf(a2, bB.x, acc[2][4]); acc[2][5] = fmaf(a2, bB.y, acc[2][5]);
        acc[2][6] = fmaf(a2, bB.z, acc[2][6]); acc[2][7] = fmaf(a2, bB.w, acc[2][7]);
        acc[3][0] = fmaf(a3, bA.x, acc[3][0]); acc[3][1] = fmaf(a3, bA.y, acc[3][1]);
        acc[3][2] = fmaf(a3, bA.z, acc[3][2]); acc[3][3] = fmaf(a3, bA.w, acc[3][3]);
        acc[3][4] = fmaf(a3, bB.x, acc[3][4]); acc[3][5] = fmaf(a3, bB.y, acc[3][5]);
        acc[3][6] = fmaf(a3, bB.z, acc[3][6]); acc[3][7] = fmaf(a3, bB.w, acc[3][7]);
      }
      __syncthreads();
    }
  }

  float4 c0 = *(const float4*)&b1[tx * 4];
  float4 c1 = *(const float4*)&b1[64 + tx * 4];
  if constexpr (TWO) {
    float4 d0 = *(const float4*)&b2[tx * 4];
    float4 d1 = *(const float4*)&b2[64 + tx * 4];
    c0.x += d0.x; c0.y += d0.y; c0.z += d0.z; c0.w += d0.w;
    c1.x += d1.x; c1.y += d1.y; c1.z += d1.z; c1.w += d1.w;
  }
#pragma unroll
  for (int i = 0; i < 4; ++i) {
    int gr = r0 + ty * 4 + i;
    if (gr < nrows) {
      float4 o0, o1;
      o0.x = fmaxf(acc[i][0] + c0.x, 0.f);
      o0.y = fmaxf(acc[i][1] + c0.y, 0.f);
      o0.z = fmaxf(acc[i][2] + c0.z, 0.f);
      o0.w = fmaxf(acc[i][3] + c0.w, 0.f);
      o1.x = fmaxf(acc[i][4] + c1.x, 0.f);
      o1.y = fmaxf(acc[i][5] + c1.y, 0.f);
      o1.z = fmaxf(acc[i][6] + c1.z, 0.f);
      o1.w = fmaxf(acc[i][7] + c1.w, 0.f);
      *(float4*)(out + (size_t)gr * D + tx * 4) = o0;
      *(float4*)(out + (size_t)gr * D + 64 + tx * 4) = o1;
    }
  }
}

// ---------------- per-graph mean pooling (sorted gid -> segment partials) ----------------
#define PCHUNK 256
__global__ __launch_bounds__(128) void k_pool(const float* __restrict__ H,
                                              const int* __restrict__ gid,
                                              float* __restrict__ sums,
                                              float* __restrict__ cnt, int n) {
  int col = threadIdx.x;
  int start = blockIdx.x * PCHUNK;
  if (start >= n) return;
  int end = min(start + PCHUNK, n);
  float acc = 0.f;
  int cur = gid[start];
  int seglen = 0;
  for (int r = start; r < end; ++r) {
    int g = gid[r];
    if (g != cur) {
      atomicAdd(&sums[cur * D + col], acc);
      if (col == 0) atomicAdd(&cnt[cur], (float)seglen);
      acc = 0.f; seglen = 0; cur = g;
    }
    acc += H[(size_t)r * D + col];
    seglen++;
  }
  atomicAdd(&sums[cur * D + col], acc);
  if (col == 0) atomicAdd(&cnt[cur], (float)seglen);
}

// ---------------- final MLP on [16,128] ----------------
__global__ __launch_bounds__(256) void k_final(const float* __restrict__ sums,
                                               const float* __restrict__ cnt,
                                               const float* __restrict__ Wm1,
                                               const float* __restrict__ bm1,
                                               const float* __restrict__ Wm2,
                                               const float* __restrict__ bm2,
                                               float* __restrict__ out) {
  __shared__ float hg[16][128];
  __shared__ float t1[16][128];
  int tid = threadIdx.x;
  for (int i = tid; i < 16 * 128; i += 256) {
    int g = i >> 7, c = i & 127;
    hg[g][c] = sums[i] / fmaxf(cnt[g], 1.f);
  }
  __syncthreads();
  for (int i = tid; i < 16 * 128; i += 256) {
    int g = i >> 7, c = i & 127;
    float a = bm1[c];
    for (int k = 0; k < 128; ++k) a = fmaf(hg[g][k], Wm1[k * 128 + c], a);
    t1[g][c] = fmaxf(a, 0.f);
  }
  __syncthreads();
  int g = tid >> 4, l = tid & 15;
  float p = 0.f;
  for (int c = l; c < 128; c += 16) p = fmaf(t1[g][c], Wm2[c], p);
#pragma unroll
  for (int o = 8; o; o >>= 1) p += __shfl_down(p, o, 16);
  if (l == 0) out[g] = p + bm2[0];
}

extern "C" void kernel_launch(void* const* d_in, const int* in_sizes, int n_in,
                              void* d_out, int out_size, void* d_ws, size_t ws_size,
                              hipStream_t stream) {
  const float* x_tile = (const float*)d_in[0];
  const float* x_rr   = (const float*)d_in[1];
  const int* tt_src = (const int*)d_in[2];
  const int* tt_dst = (const int*)d_in[3];
  const int* rt_src = (const int*)d_in[4];
  const int* rt_dst = (const int*)d_in[5];
  const int* tr_src = (const int*)d_in[6];
  const int* tr_dst = (const int*)d_in[7];
  const int* tile_gid = (const int*)d_in[8];
  const float* W1_tt = (const float*)d_in[9];  const float* b1_tt = (const float*)d_in[10];
  const float* W1_rt = (const float*)d_in[11]; const float* b1_rt = (const float*)d_in[12];
  const float* W1_tr = (const float*)d_in[13]; const float* b1_tr = (const float*)d_in[14];
  const float* W2_tt = (const float*)d_in[15]; const float* b2_tt = (const float*)d_in[16];
  const float* W2_rt = (const float*)d_in[17]; const float* b2_rt = (const float*)d_in[18];
  const float* Wm1 = (const float*)d_in[21]; const float* bm1 = (const float*)d_in[22];
  const float* Wm2 = (const float*)d_in[23]; const float* bm2 = (const float*)d_in[24];

  char* ws = (char*)d_ws;
  size_t off = 0;
  auto alloc = [&](size_t elems) {
    void* p = ws + off;
    off += (elems * 4 + 255) & ~(size_t)255;
    return p;
  };
  // ---- zero region (memset each call) ----
  int* ideg_tt = (int*)alloc(N_TILE);
  int* odeg_tt = (int*)alloc(N_TILE);
  int* ideg_rt = (int*)alloc(N_TILE);
  int* odeg_rt = (int*)alloc(N_RR);
  int* ideg_tr = (int*)alloc(N_RR);
  int* odeg_tr = (int*)alloc(N_TILE);
  int* cur_tt = (int*)alloc(N_TILE);
  int* cur_rt = (int*)alloc(N_TILE);
  int* cur_tr = (int*)alloc(N_RR);
  float* psum = (float*)alloc(N_G * D);
  float* pcnt = (float*)alloc(N_G);
  size_t zero_bytes = off;
  // ---- rest ----
  int* pp_tt = (int*)alloc(N_TILE);
  int* pp_rt = (int*)alloc(N_TILE);
  int* pp_tr = (int*)alloc(N_RR);
  int* bsum = (int*)alloc(3 * NB);
  int* bs = (int*)alloc(3 * (NB + 1));
  int* rp_tt = (int*)alloc(N_TILE + 1);
  int* rp_rt = (int*)alloc(N_TILE + 1);
  int* rp_tr = (int*)alloc(N_RR + 1);
  int* csr_tt = (int*)alloc(E_TT);
  int* csr_rt = (int*)alloc(E_RT);
  int* csr_tr = (int*)alloc(E_TR);
  float* osc_tt = (float*)alloc(N_TILE);
  float* isc_tt = (float*)alloc(N_TILE);
  float* osc_rt = (float*)alloc(N_RR);
  float* isc_rt = (float*)alloc(N_TILE);
  float* osc_tr = (float*)alloc(N_TILE);
  float* isc_tr = (float*)alloc(N_RR);
  float* Abuf = (float*)alloc((size_t)N_TILE * D);
  float* Bbuf = (float*)alloc((size_t)N_TILE * D);
  float* Htile = (float*)alloc((size_t)N_TILE * D);
  float* Hrr = (float*)alloc((size_t)N_RR * D);
  (void)ws_size; (void)in_sizes; (void)n_in; (void)out_size;

  hipMemsetAsync(d_ws, 0, zero_bytes, stream);

  // ---- CSR build (edges identical for both layers -> build once) ----
  k_hist_all<<<(E_ALL + 255) / 256, 256, 0, stream>>>(
      tt_src, tt_dst, rt_src, rt_dst, tr_src, tr_dst,
      odeg_tt, ideg_tt, odeg_rt, ideg_rt, odeg_tr, ideg_tr);
  k_scan1<<<3 * NB, 1024, 0, stream>>>(ideg_tt, ideg_rt, ideg_tr, pp_tt, pp_rt, pp_tr, bsum);
  k_scan2<<<1, 256, 0, stream>>>(bsum, bs);
  k_finalize<<<(N_TILE + 255) / 256, 256, 0, stream>>>(
      pp_tt, pp_rt, pp_tr, bs, rp_tt, rp_rt, rp_tr,
      odeg_tt, ideg_tt, odeg_rt, ideg_rt, odeg_tr, ideg_tr,
      osc_tt, isc_tt, osc_rt, isc_rt, osc_tr, isc_tr);
  k_fill_all<<<(E_ALL + 255) / 256, 256, 0, stream>>>(
      tt_src, tt_dst, rt_src, rt_dst, tr_src, tr_dst,
      rp_tt, rp_rt, rp_tr, cur_tt, cur_rt, cur_tr, csr_tt, csr_rt, csr_tr);

  const int gemmBlocks = (N_TILE + GBM - 1) / GBM;

  // ---- layer 1: all three aggs fused (tr output parked in Htile) ----
  {
    int totw = N_TILE + N_TILE + N_RR;
    k_agg3<<<(totw * 64 + 255) / 256, 256, 0, stream>>>(
        x_tile, rp_tt, csr_tt, osc_tt, isc_tt, Abuf, N_TILE,
        x_rr,  rp_rt, csr_rt, osc_rt, isc_rt, Bbuf, N_TILE,
        x_tile, rp_tr, csr_tr, osc_tr, isc_tr, Htile, N_RR);
  }
  // tr GEMM first (consumes Htile before it is overwritten)
  k_gemm<false><<<gemmBlocks, 256, 0, stream>>>(Htile, nullptr, W1_tr, nullptr, b1_tr, nullptr, Hrr, N_RR);
  k_gemm<true><<<gemmBlocks, 256, 0, stream>>>(Abuf, Bbuf, W1_tt, W1_rt, b1_tt, b1_rt, Htile, N_TILE);

  // ---- layer 2 (h2_rr never consumed -> tr relation skipped) ----
  {
    int totw = N_TILE + N_TILE;
    k_agg3<<<(totw * 64 + 255) / 256, 256, 0, stream>>>(
        Htile, rp_tt, csr_tt, osc_tt, isc_tt, Abuf, N_TILE,
        Hrr,   rp_rt, csr_rt, osc_rt, isc_rt, Bbuf, N_TILE,
        nullptr, nullptr, nullptr, nullptr, nullptr, nullptr, 0);
  }
  k_gemm<true><<<gemmBlocks, 256, 0, stream>>>(Abuf, Bbuf, W2_tt, W2_rt, b2_tt, b2_rt, Htile, N_TILE);

  // ---- pooling + MLP head ----
  k_pool<<<(N_TILE + PCHUNK - 1) / PCHUNK, 128, 0, stream>>>(Htile, tile_gid, psum, pcnt, N_TILE);
  k_final<<<1, 256, 0, stream>>>(psum, pcnt, Wm1, bm1, Wm2, bm2, (float*)d_out);
}

// Round 4
// 642.200 us; speedup vs baseline: 1.3337x; 1.1430x over previous
//
#include <hip/hip_runtime.h>

#define N_TILE 50000
#define N_RR   50000
#define D      128
#define E_TT   800000
#define E_RT   400000
#define E_TR   400000
#define N_G    16
#define NB     ((N_TILE + 1023) / 1024)   // scan blocks per array (=49)
#define E_ALL  (E_TT + E_RT + E_TR)

static_assert(NB <= 64, "scan2 uses one wave per array");

// ---------------- fused histogram (degrees, all 3 relations) ----------------
__global__ void k_hist_all(const int* __restrict__ tt_src, const int* __restrict__ tt_dst,
                           const int* __restrict__ rt_src, const int* __restrict__ rt_dst,
                           const int* __restrict__ tr_src, const int* __restrict__ tr_dst,
                           int* __restrict__ od_tt, int* __restrict__ id_tt,
                           int* __restrict__ od_rt, int* __restrict__ id_rt,
                           int* __restrict__ od_tr, int* __restrict__ id_tr) {
  int i = blockIdx.x * blockDim.x + threadIdx.x;
  if (i >= E_ALL) return;
  if (i < E_TT) {
    atomicAdd(&od_tt[tt_src[i]], 1);
    atomicAdd(&id_tt[tt_dst[i]], 1);
  } else if (i < E_TT + E_RT) {
    int j = i - E_TT;
    atomicAdd(&od_rt[rt_src[j]], 1);
    atomicAdd(&id_rt[rt_dst[j]], 1);
  } else {
    int j = i - E_TT - E_RT;
    atomicAdd(&od_tr[tr_src[j]], 1);
    atomicAdd(&id_tr[tr_dst[j]], 1);
  }
}

// ---------------- scan stage 1: per-block exclusive scan (1024 elems/block) ----------------
__global__ __launch_bounds__(1024) void k_scan1(const int* __restrict__ d0,
                                                const int* __restrict__ d1,
                                                const int* __restrict__ d2,
                                                int* __restrict__ p0,
                                                int* __restrict__ p1,
                                                int* __restrict__ p2,
                                                int* __restrict__ bsum) {
  int arr = blockIdx.x / NB;
  int blk = blockIdx.x % NB;
  const int* deg = arr == 0 ? d0 : (arr == 1 ? d1 : d2);
  int* part = arr == 0 ? p0 : (arr == 1 ? p1 : p2);
  __shared__ int ts[1024];
  int tid = threadIdx.x;
  int i = blk * 1024 + tid;
  int v = (i < N_TILE) ? deg[i] : 0;
  ts[tid] = v;
  __syncthreads();
  for (int d = 1; d < 1024; d <<= 1) {
    int t = (tid >= d) ? ts[tid - d] : 0;
    __syncthreads();
    ts[tid] += t;
    __syncthreads();
  }
  if (i < N_TILE) part[i] = ts[tid] - v;   // exclusive within block
  if (tid == 1023) bsum[arr * NB + blk] = ts[1023];
}

// ---------------- scan stage 2: scan the block sums (1 wave / array) ----------------
__global__ __launch_bounds__(256) void k_scan2(const int* __restrict__ bsum,
                                               int* __restrict__ bs) {
  int wv = threadIdx.x >> 6;
  int lane = threadIdx.x & 63;
  if (wv >= 3) return;
  int v = (lane < NB) ? bsum[wv * NB + lane] : 0;
  int orig = v;
#pragma unroll
  for (int o = 1; o < 64; o <<= 1) {
    int t = __shfl_up(v, o);
    if (lane >= o) v += t;
  }
  if (lane < NB) bs[wv * (NB + 1) + lane] = v - orig;   // exclusive
  if (lane == NB - 1) bs[wv * (NB + 1) + NB] = v;       // total
}

// ---------------- finalize: rp = part + block offset; in-degree -> isc ----------------
__global__ void k_finalize(const int* __restrict__ pp_tt, const int* __restrict__ pp_rt,
                           const int* __restrict__ pp_tr, const int* __restrict__ bs,
                           int* __restrict__ rp_tt, int* __restrict__ rp_rt,
                           int* __restrict__ rp_tr,
                           const int* __restrict__ id_tt, const int* __restrict__ id_rt,
                           const int* __restrict__ id_tr,
                           float* __restrict__ is_tt, float* __restrict__ is_rt,
                           float* __restrict__ is_tr) {
  int i = blockIdx.x * blockDim.x + threadIdx.x;
  if (i >= N_TILE) return;
  int b = i >> 10;
  rp_tt[i] = pp_tt[i] + bs[0 * (NB + 1) + b];
  rp_rt[i] = pp_rt[i] + bs[1 * (NB + 1) + b];
  rp_tr[i] = pp_tr[i] + bs[2 * (NB + 1) + b];
  if (i == 0) {
    rp_tt[N_TILE] = bs[0 * (NB + 1) + NB];
    rp_rt[N_TILE] = bs[1 * (NB + 1) + NB];
    rp_tr[N_RR] = bs[2 * (NB + 1) + NB];
  }
  is_tt[i] = rsqrtf((float)max(id_tt[i], 1));
  is_rt[i] = rsqrtf((float)max(id_rt[i], 1));
  is_tr[i] = rsqrtf((float)max(id_tr[i], 1));
}

// ---------------- fused CSR fill: writes (src, osc[src]) pairs ----------------
__global__ void k_fill_all(const int* __restrict__ tt_src, const int* __restrict__ tt_dst,
                           const int* __restrict__ rt_src, const int* __restrict__ rt_dst,
                           const int* __restrict__ tr_src, const int* __restrict__ tr_dst,
                           const int* __restrict__ rp_tt, const int* __restrict__ rp_rt,
                           const int* __restrict__ rp_tr,
                           const int* __restrict__ od_tt, const int* __restrict__ od_rt,
                           const int* __restrict__ od_tr,
                           int* __restrict__ cur_tt, int* __restrict__ cur_rt,
                           int* __restrict__ cur_tr,
                           int2* __restrict__ pr_tt, int2* __restrict__ pr_rt,
                           int2* __restrict__ pr_tr) {
  int i = blockIdx.x * blockDim.x + threadIdx.x;
  if (i >= E_ALL) return;
  const int* src; const int* dst; const int* rp; const int* od; int* cur; int2* pr; int j;
  if (i < E_TT) { j = i; src = tt_src; dst = tt_dst; rp = rp_tt; od = od_tt; cur = cur_tt; pr = pr_tt; }
  else if (i < E_TT + E_RT) { j = i - E_TT; src = rt_src; dst = rt_dst; rp = rp_rt; od = od_rt; cur = cur_rt; pr = pr_rt; }
  else { j = i - E_TT - E_RT; src = tr_src; dst = tr_dst; rp = rp_tr; od = od_tr; cur = cur_tr; pr = pr_tr; }
  int d = dst[j];
  int s = src[j];
  int p = atomicAdd(&cur[d], 1);
  int2 v;
  v.x = s;
  v.y = __float_as_int(rsqrtf((float)max(od[s], 1)));
  pr[rp[d] + p] = v;
}

// ---------------- fused aggregation: up to 3 relations, one wave per dst ----------------
// out[d] = isc[d] * sum_e w_e * x[src_e];  pairs pr[e] = (src_e, w_e)
// Half-wave layout: lanes 0-31 and 32-63 each load a full 512B row as float4
// -> one load instruction covers TWO edges. 4 rows in flight per half-wave.
__global__ __launch_bounds__(256) void k_agg3(
    const float* __restrict__ x0, const int* __restrict__ rp0, const int2* __restrict__ pr0,
    const float* __restrict__ isc0, float* __restrict__ out0, int n0,
    const float* __restrict__ x1, const int* __restrict__ rp1, const int2* __restrict__ pr1,
    const float* __restrict__ isc1, float* __restrict__ out1, int n1,
    const float* __restrict__ x2, const int* __restrict__ rp2, const int2* __restrict__ pr2,
    const float* __restrict__ isc2, float* __restrict__ out2, int n2) {
  int gw = (blockIdx.x * blockDim.x + threadIdx.x) >> 6;
  int lane = threadIdx.x & 63;
  int half = lane >> 5;      // which edge of the pair
  int l5 = lane & 31;        // float4 slot within the 128-float row
  const float* x; const int* rp; const int2* pr; const float* isc; float* out; int wid;
  if (gw < n0) { x = x0; rp = rp0; pr = pr0; isc = isc0; out = out0; wid = gw; }
  else if (gw < n0 + n1) { x = x1; rp = rp1; pr = pr1; isc = isc1; out = out1; wid = gw - n0; }
  else if (gw < n0 + n1 + n2) { x = x2; rp = rp2; pr = pr2; isc = isc2; out = out2; wid = gw - n0 - n1; }
  else return;
  int beg = rp[wid], end = rp[wid + 1];
  float4 a0 = make_float4(0.f, 0.f, 0.f, 0.f);
  float4 a1 = a0, a2 = a0, a3 = a0;
  const float4* xb = (const float4*)x + l5;
  for (int e = beg; e < end; e += 8) {
    int2 p0, p1, p2, p3;
    float w0, w1, w2, w3;
    {
      int i0 = e + 0 + half, i1 = e + 2 + half, i2 = e + 4 + half, i3 = e + 6 + half;
      int lim = end - 1;
      p0 = pr[min(i0, lim)];
      p1 = pr[min(i1, lim)];
      p2 = pr[min(i2, lim)];
      p3 = pr[min(i3, lim)];
      w0 = (i0 < end) ? __int_as_float(p0.y) : 0.f;
      w1 = (i1 < end) ? __int_as_float(p1.y) : 0.f;
      w2 = (i2 < end) ? __int_as_float(p2.y) : 0.f;
      w3 = (i3 < end) ? __int_as_float(p3.y) : 0.f;
    }
    float4 v0 = xb[(size_t)p0.x * 32];
    float4 v1 = xb[(size_t)p1.x * 32];
    float4 v2 = xb[(size_t)p2.x * 32];
    float4 v3 = xb[(size_t)p3.x * 32];
    a0.x = fmaf(v0.x, w0, a0.x); a0.y = fmaf(v0.y, w0, a0.y);
    a0.z = fmaf(v0.z, w0, a0.z); a0.w = fmaf(v0.w, w0, a0.w);
    a1.x = fmaf(v1.x, w1, a1.x); a1.y = fmaf(v1.y, w1, a1.y);
    a1.z = fmaf(v1.z, w1, a1.z); a1.w = fmaf(v1.w, w1, a1.w);
    a2.x = fmaf(v2.x, w2, a2.x); a2.y = fmaf(v2.y, w2, a2.y);
    a2.z = fmaf(v2.z, w2, a2.z); a2.w = fmaf(v2.w, w2, a2.w);
    a3.x = fmaf(v3.x, w3, a3.x); a3.y = fmaf(v3.y, w3, a3.y);
    a3.z = fmaf(v3.z, w3, a3.z); a3.w = fmaf(v3.w, w3, a3.w);
  }
  float4 s;
  s.x = (a0.x + a1.x) + (a2.x + a3.x);
  s.y = (a0.y + a1.y) + (a2.y + a3.y);
  s.z = (a0.z + a1.z) + (a2.z + a3.z);
  s.w = (a0.w + a1.w) + (a2.w + a3.w);
  // combine the two half-wave edge sets
  s.x += __shfl_xor(s.x, 32);
  s.y += __shfl_xor(s.y, 32);
  s.z += __shfl_xor(s.z, 32);
  s.w += __shfl_xor(s.w, 32);
  if (half == 0) {
    float iv = isc[wid];
    float4 r;
    r.x = s.x * iv; r.y = s.y * iv; r.z = s.z * iv; r.w = s.w * iv;
    ((float4*)(out + (size_t)wid * D))[l5] = r;
  }
}

// ---------------- fused GEMM(+GEMM) + bias + relu ----------------
// out[r][c] = relu( A[r,:]@W1[:,c] (+ B[r,:]@W2[:,c]) + b1[c] (+ b2[c]) )
#define GBM 64
#define GKC 32

template<bool TWO>
__global__ __launch_bounds__(256) void k_gemm(const float* __restrict__ A,
                                              const float* __restrict__ B,
                                              const float* __restrict__ W1,
                                              const float* __restrict__ W2,
                                              const float* __restrict__ b1,
                                              const float* __restrict__ b2,
                                              float* __restrict__ out, int nrows) {
  __shared__ float As[GBM][GKC + 1];
  __shared__ float Ws[GKC][132];
  int tid = threadIdx.x;
  int tx = tid & 15, ty = tid >> 4;
  int r0 = blockIdx.x * GBM;
  float acc[4][8];
#pragma unroll
  for (int i = 0; i < 4; ++i)
#pragma unroll
    for (int j = 0; j < 8; ++j) acc[i][j] = 0.f;

  const int nrel = TWO ? 2 : 1;
  for (int rel = 0; rel < nrel; ++rel) {
    const float* __restrict__ Xp = (rel == 0) ? A : B;
    const float* __restrict__ Wp = (rel == 0) ? W1 : W2;
    for (int k0 = 0; k0 < D; k0 += GKC) {
      {
        int lr = tid >> 3;
        int lk = (tid & 7) * 4;
#pragma unroll
        for (int h = 0; h < 2; ++h) {
          int rr = lr + h * 32;
          int gr = r0 + rr;
          float4 v = make_float4(0.f, 0.f, 0.f, 0.f);
          if (gr < nrows) v = *(const float4*)(Xp + (size_t)gr * D + k0 + lk);
          As[rr][lk] = v.x; As[rr][lk + 1] = v.y; As[rr][lk + 2] = v.z; As[rr][lk + 3] = v.w;
        }
        int wk = tid >> 5;
        int wc = (tid & 31) * 4;
#pragma unroll
        for (int h = 0; h < 4; ++h) {
          int kk = wk + h * 8;
          float4 v = *(const float4*)(Wp + (size_t)(k0 + kk) * D + wc);
          *(float4*)&Ws[kk][wc] = v;
        }
      }
      __syncthreads();
#pragma unroll 8
      for (int k = 0; k < GKC; ++k) {
        float a0 = As[ty * 4 + 0][k];
        float a1 = As[ty * 4 + 1][k];
        float a2 = As[ty * 4 + 2][k];
        float a3 = As[ty * 4 + 3][k];
        float4 bA = *(const float4*)&Ws[k][tx * 4];
        float4 bB = *(const float4*)&Ws[k][64 + tx * 4];
        acc[0][0] = fmaf(a0, bA.x, acc[0][0]); acc[0][1] = fmaf(a0, bA.y, acc[0][1]);
        acc[0][2] = fmaf(a0, bA.z, acc[0][2]); acc[0][3] = fmaf(a0, bA.w, acc[0][3]);
        acc[0][4] = fmaf(a0, bB.x, acc[0][4]); acc[0][5] = fmaf(a0, bB.y, acc[0][5]);
        acc[0][6] = fmaf(a0, bB.z, acc[0][6]); acc[0][7] = fmaf(a0, bB.w, acc[0][7]);
        acc[1][0] = fmaf(a1, bA.x, acc[1][0]); acc[1][1] = fmaf(a1, bA.y, acc[1][1]);
        acc[1][2] = fmaf(a1, bA.z, acc[1][2]); acc[1][3] = fmaf(a1, bA.w, acc[1][3]);
        acc[1][4] = fmaf(a1, bB.x, acc[1][4]); acc[1][5] = fmaf(a1, bB.y, acc[1][5]);
        acc[1][6] = fmaf(a1, bB.z, acc[1][6]); acc[1][7] = fmaf(a1, bB.w, acc[1][7]);
        acc[2][0] = fmaf(a2, bA.x, acc[2][0]); acc[2][1] = fmaf(a2, bA.y, acc[2][1]);
        acc[2][2] = fmaf(a2, bA.z, acc[2][2]); acc[2][3] = fmaf(a2, bA.w, acc[2][3]);
        acc[2][4] = fmaf(a2, bB.x, acc[2][4]); acc[2][5] = fmaf(a2, bB.y, acc[2][5]);
        acc[2][6] = fmaf(a2, bB.z, acc[2][6]); acc[2][7] = fmaf(a2, bB.w, acc[2][7]);
        acc[3][0] = fmaf(a3, bA.x, acc[3][0]); acc[3][1] = fmaf(a3, bA.y, acc[3][1]);
        acc[3][2] = fmaf(a3, bA.z, acc[3][2]); acc[3][3] = fmaf(a3, bA.w, acc[3][3]);
        acc[3][4] = fmaf(a3, bB.x, acc[3][4]); acc[3][5] = fmaf(a3, bB.y, acc[3][5]);
        acc[3][6] = fmaf(a3, bB.z, acc[3][6]); acc[3][7] = fmaf(a3, bB.w, acc[3][7]);
      }
      __syncthreads();
    }
  }

  float4 c0 = *(const float4*)&b1[tx * 4];
  float4 c1 = *(const float4*)&b1[64 + tx * 4];
  if constexpr (TWO) {
    float4 d0 = *(const float4*)&b2[tx * 4];
    float4 d1 = *(const float4*)&b2[64 + tx * 4];
    c0.x += d0.x; c0.y += d0.y; c0.z += d0.z; c0.w += d0.w;
    c1.x += d1.x; c1.y += d1.y; c1.z += d1.z; c1.w += d1.w;
  }
#pragma unroll
  for (int i = 0; i < 4; ++i) {
    int gr = r0 + ty * 4 + i;
    if (gr < nrows) {
      float4 o0, o1;
      o0.x = fmaxf(acc[i][0] + c0.x, 0.f);
      o0.y = fmaxf(acc[i][1] + c0.y, 0.f);
      o0.z = fmaxf(acc[i][2] + c0.z, 0.f);
      o0.w = fmaxf(acc[i][3] + c0.w, 0.f);
      o1.x = fmaxf(acc[i][4] + c1.x, 0.f);
      o1.y = fmaxf(acc[i][5] + c1.y, 0.f);
      o1.z = fmaxf(acc[i][6] + c1.z, 0.f);
      o1.w = fmaxf(acc[i][7] + c1.w, 0.f);
      *(float4*)(out + (size_t)gr * D + tx * 4) = o0;
      *(float4*)(out + (size_t)gr * D + 64 + tx * 4) = o1;
    }
  }
}

// ---------------- per-graph mean pooling (sorted gid -> segment partials) ----------------
#define PCHUNK 256
__global__ __launch_bounds__(128) void k_pool(const float* __restrict__ H,
                                              const int* __restrict__ gid,
                                              float* __restrict__ sums,
                                              float* __restrict__ cnt, int n) {
  int col = threadIdx.x;
  int start = blockIdx.x * PCHUNK;
  if (start >= n) return;
  int end = min(start + PCHUNK, n);
  float acc = 0.f;
  int cur = gid[start];
  int seglen = 0;
  for (int r = start; r < end; ++r) {
    int g = gid[r];
    if (g != cur) {
      atomicAdd(&sums[cur * D + col], acc);
      if (col == 0) atomicAdd(&cnt[cur], (float)seglen);
      acc = 0.f; seglen = 0; cur = g;
    }
    acc += H[(size_t)r * D + col];
    seglen++;
  }
  atomicAdd(&sums[cur * D + col], acc);
  if (col == 0) atomicAdd(&cnt[cur], (float)seglen);
}

// ---------------- final MLP on [16,128] ----------------
__global__ __launch_bounds__(256) void k_final(const float* __restrict__ sums,
                                               const float* __restrict__ cnt,
                                               const float* __restrict__ Wm1,
                                               const float* __restrict__ bm1,
                                               const float* __restrict__ Wm2,
                                               const float* __restrict__ bm2,
                                               float* __restrict__ out) {
  __shared__ float hg[16][128];
  __shared__ float t1[16][128];
  int tid = threadIdx.x;
  for (int i = tid; i < 16 * 128; i += 256) {
    int g = i >> 7, c = i & 127;
    hg[g][c] = sums[i] / fmaxf(cnt[g], 1.f);
  }
  __syncthreads();
  for (int i = tid; i < 16 * 128; i += 256) {
    int g = i >> 7, c = i & 127;
    float a = bm1[c];
    for (int k = 0; k < 128; ++k) a = fmaf(hg[g][k], Wm1[k * 128 + c], a);
    t1[g][c] = fmaxf(a, 0.f);
  }
  __syncthreads();
  int g = tid >> 4, l = tid & 15;
  float p = 0.f;
  for (int c = l; c < 128; c += 16) p = fmaf(t1[g][c], Wm2[c], p);
#pragma unroll
  for (int o = 8; o; o >>= 1) p += __shfl_down(p, o, 16);
  if (l == 0) out[g] = p + bm2[0];
}

extern "C" void kernel_launch(void* const* d_in, const int* in_sizes, int n_in,
                              void* d_out, int out_size, void* d_ws, size_t ws_size,
                              hipStream_t stream) {
  const float* x_tile = (const float*)d_in[0];
  const float* x_rr   = (const float*)d_in[1];
  const int* tt_src = (const int*)d_in[2];
  const int* tt_dst = (const int*)d_in[3];
  const int* rt_src = (const int*)d_in[4];
  const int* rt_dst = (const int*)d_in[5];
  const int* tr_src = (const int*)d_in[6];
  const int* tr_dst = (const int*)d_in[7];
  const int* tile_gid = (const int*)d_in[8];
  const float* W1_tt = (const float*)d_in[9];  const float* b1_tt = (const float*)d_in[10];
  const float* W1_rt = (const float*)d_in[11]; const float* b1_rt = (const float*)d_in[12];
  const float* W1_tr = (const float*)d_in[13]; const float* b1_tr = (const float*)d_in[14];
  const float* W2_tt = (const float*)d_in[15]; const float* b2_tt = (const float*)d_in[16];
  const float* W2_rt = (const float*)d_in[17]; const float* b2_rt = (const float*)d_in[18];
  const float* Wm1 = (const float*)d_in[21]; const float* bm1 = (const float*)d_in[22];
  const float* Wm2 = (const float*)d_in[23]; const float* bm2 = (const float*)d_in[24];

  char* ws = (char*)d_ws;
  size_t off = 0;
  auto alloc = [&](size_t elems) {
    void* p = ws + off;
    off += (elems * 4 + 255) & ~(size_t)255;
    return p;
  };
  // ---- zero region (memset each call) ----
  int* ideg_tt = (int*)alloc(N_TILE);
  int* odeg_tt = (int*)alloc(N_TILE);
  int* ideg_rt = (int*)alloc(N_TILE);
  int* odeg_rt = (int*)alloc(N_RR);
  int* ideg_tr = (int*)alloc(N_RR);
  int* odeg_tr = (int*)alloc(N_TILE);
  int* cur_tt = (int*)alloc(N_TILE);
  int* cur_rt = (int*)alloc(N_TILE);
  int* cur_tr = (int*)alloc(N_RR);
  float* psum = (float*)alloc(N_G * D);
  float* pcnt = (float*)alloc(N_G);
  size_t zero_bytes = off;
  // ---- rest ----
  int* pp_tt = (int*)alloc(N_TILE);
  int* pp_rt = (int*)alloc(N_TILE);
  int* pp_tr = (int*)alloc(N_RR);
  int* bsum = (int*)alloc(3 * NB);
  int* bs = (int*)alloc(3 * (NB + 1));
  int* rp_tt = (int*)alloc(N_TILE + 1);
  int* rp_rt = (int*)alloc(N_TILE + 1);
  int* rp_tr = (int*)alloc(N_RR + 1);
  int2* pr_tt = (int2*)alloc((size_t)E_TT * 2);
  int2* pr_rt = (int2*)alloc((size_t)E_RT * 2);
  int2* pr_tr = (int2*)alloc((size_t)E_TR * 2);
  float* isc_tt = (float*)alloc(N_TILE);
  float* isc_rt = (float*)alloc(N_TILE);
  float* isc_tr = (float*)alloc(N_RR);
  float* Abuf = (float*)alloc((size_t)N_TILE * D);
  float* Bbuf = (float*)alloc((size_t)N_TILE * D);
  float* Htile = (float*)alloc((size_t)N_TILE * D);
  float* Hrr = (float*)alloc((size_t)N_RR * D);
  (void)ws_size; (void)in_sizes; (void)n_in; (void)out_size;

  hipMemsetAsync(d_ws, 0, zero_bytes, stream);

  // ---- CSR build (edges identical for both layers -> build once) ----
  k_hist_all<<<(E_ALL + 255) / 256, 256, 0, stream>>>(
      tt_src, tt_dst, rt_src, rt_dst, tr_src, tr_dst,
      odeg_tt, ideg_tt, odeg_rt, ideg_rt, odeg_tr, ideg_tr);
  k_scan1<<<3 * NB, 1024, 0, stream>>>(ideg_tt, ideg_rt, ideg_tr, pp_tt, pp_rt, pp_tr, bsum);
  k_scan2<<<1, 256, 0, stream>>>(bsum, bs);
  k_finalize<<<(N_TILE + 255) / 256, 256, 0, stream>>>(
      pp_tt, pp_rt, pp_tr, bs, rp_tt, rp_rt, rp_tr,
      ideg_tt, ideg_rt, ideg_tr, isc_tt, isc_rt, isc_tr);
  k_fill_all<<<(E_ALL + 255) / 256, 256, 0, stream>>>(
      tt_src, tt_dst, rt_src, rt_dst, tr_src, tr_dst,
      rp_tt, rp_rt, rp_tr, odeg_tt, odeg_rt, odeg_tr,
      cur_tt, cur_rt, cur_tr, pr_tt, pr_rt, pr_tr);

  const int gemmBlocks = (N_TILE + GBM - 1) / GBM;

  // ---- layer 1: all three aggs fused (tr output parked in Htile) ----
  {
    int totw = N_TILE + N_TILE + N_RR;
    k_agg3<<<(totw * 64 + 255) / 256, 256, 0, stream>>>(
        x_tile, rp_tt, pr_tt, isc_tt, Abuf, N_TILE,
        x_rr,  rp_rt, pr_rt, isc_rt, Bbuf, N_TILE,
        x_tile, rp_tr, pr_tr, isc_tr, Htile, N_RR);
  }
  // tr GEMM first (consumes Htile before it is overwritten)
  k_gemm<false><<<gemmBlocks, 256, 0, stream>>>(Htile, nullptr, W1_tr, nullptr, b1_tr, nullptr, Hrr, N_RR);
  k_gemm<true><<<gemmBlocks, 256, 0, stream>>>(Abuf, Bbuf, W1_tt, W1_rt, b1_tt, b1_rt, Htile, N_TILE);

  // ---- layer 2 (h2_rr never consumed -> tr relation skipped) ----
  {
    int totw = N_TILE + N_TILE;
    k_agg3<<<(totw * 64 + 255) / 256, 256, 0, stream>>>(
        Htile, rp_tt, pr_tt, isc_tt, Abuf, N_TILE,
        Hrr,   rp_rt, pr_rt, isc_rt, Bbuf, N_TILE,
        nullptr, nullptr, nullptr, nullptr, nullptr, 0);
  }
  k_gemm<true><<<gemmBlocks, 256, 0, stream>>>(Abuf, Bbuf, W2_tt, W2_rt, b2_tt, b2_rt, Htile, N_TILE);

  // ---- pooling + MLP head ----
  k_pool<<<(N_TILE + PCHUNK - 1) / PCHUNK, 128, 0, stream>>>(Htile, tile_gid, psum, pcnt, N_TILE);
  k_final<<<1, 256, 0, stream>>>(psum, pcnt, Wm1, bm1, Wm2, bm2, (float*)d_out);
}

// Round 5
// 609.679 us; speedup vs baseline: 1.4048x; 1.0533x over previous
//
#include <hip/hip_runtime.h>

#define N_TILE 50000
#define N_RR   50000
#define D      128
#define E_TT   800000
#define E_RT   400000
#define E_TR   400000
#define N_G    16
#define NB     ((N_TILE + 1023) / 1024)   // scan blocks per array (=49)
#define E_ALL  (E_TT + E_RT + E_TR)
#define NCOPY  8

static_assert(NB <= 64, "scan2 uses one wave per array");
static_assert(N_TILE == N_RR, "scan1/osc fold assumes equal node counts");

// ---------------- fused histogram + rank (degrees, all 3 relations) ----------------
// rank[e] = position of edge e within its destination's CSR segment (atomic return).
// Out-degree counts go to NCOPY block-strided copies to cut same-line contention.
__global__ void k_hist_all(const int* __restrict__ tt_src, const int* __restrict__ tt_dst,
                           const int* __restrict__ rt_src, const int* __restrict__ rt_dst,
                           const int* __restrict__ tr_src, const int* __restrict__ tr_dst,
                           int* __restrict__ id_tt, int* __restrict__ id_rt,
                           int* __restrict__ id_tr,
                           int* __restrict__ odc_tt, int* __restrict__ odc_rt,
                           int* __restrict__ odc_tr,
                           int* __restrict__ rank) {
  int i = blockIdx.x * blockDim.x + threadIdx.x;
  if (i >= E_ALL) return;
  int copy = blockIdx.x & (NCOPY - 1);
  if (i < E_TT) {
    rank[i] = atomicAdd(&id_tt[tt_dst[i]], 1);
    atomicAdd(&odc_tt[copy * N_TILE + tt_src[i]], 1);
  } else if (i < E_TT + E_RT) {
    int j = i - E_TT;
    rank[i] = atomicAdd(&id_rt[rt_dst[j]], 1);
    atomicAdd(&odc_rt[copy * N_RR + rt_src[j]], 1);
  } else {
    int j = i - E_TT - E_RT;
    rank[i] = atomicAdd(&id_tr[tr_dst[j]], 1);
    atomicAdd(&odc_tr[copy * N_TILE + tr_src[j]], 1);
  }
}

// ---------------- scan stage 1 + osc reduction ----------------
// Per-block exclusive scan of in-degrees (1024/block) + fold: osc[i] = rsqrt(sum of od copies)
__global__ __launch_bounds__(1024) void k_scan1(const int* __restrict__ d0,
                                                const int* __restrict__ d1,
                                                const int* __restrict__ d2,
                                                int* __restrict__ p0,
                                                int* __restrict__ p1,
                                                int* __restrict__ p2,
                                                int* __restrict__ bsum,
                                                const int* __restrict__ odc0,
                                                const int* __restrict__ odc1,
                                                const int* __restrict__ odc2,
                                                float* __restrict__ os0,
                                                float* __restrict__ os1,
                                                float* __restrict__ os2) {
  int arr = blockIdx.x / NB;
  int blk = blockIdx.x % NB;
  const int* deg = arr == 0 ? d0 : (arr == 1 ? d1 : d2);
  int* part = arr == 0 ? p0 : (arr == 1 ? p1 : p2);
  __shared__ int ts[1024];
  int tid = threadIdx.x;
  int i = blk * 1024 + tid;
  int v = (i < N_TILE) ? deg[i] : 0;
  ts[tid] = v;
  // osc fold (independent of the scan; overlaps the barriers)
  if (i < N_TILE) {
    const int* odc = arr == 0 ? odc0 : (arr == 1 ? odc1 : odc2);
    float* os = arr == 0 ? os0 : (arr == 1 ? os1 : os2);
    int s = 0;
#pragma unroll
    for (int c = 0; c < NCOPY; ++c) s += odc[c * N_TILE + i];
    os[i] = rsqrtf((float)max(s, 1));
  }
  __syncthreads();
  for (int d = 1; d < 1024; d <<= 1) {
    int t = (tid >= d) ? ts[tid - d] : 0;
    __syncthreads();
    ts[tid] += t;
    __syncthreads();
  }
  if (i < N_TILE) part[i] = ts[tid] - v;   // exclusive within block
  if (tid == 1023) bsum[arr * NB + blk] = ts[1023];
}

// ---------------- scan stage 2: scan the block sums (1 wave / array) ----------------
__global__ __launch_bounds__(256) void k_scan2(const int* __restrict__ bsum,
                                               int* __restrict__ bs) {
  int wv = threadIdx.x >> 6;
  int lane = threadIdx.x & 63;
  if (wv >= 3) return;
  int v = (lane < NB) ? bsum[wv * NB + lane] : 0;
  int orig = v;
#pragma unroll
  for (int o = 1; o < 64; o <<= 1) {
    int t = __shfl_up(v, o);
    if (lane >= o) v += t;
  }
  if (lane < NB) bs[wv * (NB + 1) + lane] = v - orig;   // exclusive
  if (lane == NB - 1) bs[wv * (NB + 1) + NB] = v;       // total
}

// ---------------- finalize: rp = part + block offset; in-degree -> isc ----------------
__global__ void k_finalize(const int* __restrict__ pp_tt, const int* __restrict__ pp_rt,
                           const int* __restrict__ pp_tr, const int* __restrict__ bs,
                           int* __restrict__ rp_tt, int* __restrict__ rp_rt,
                           int* __restrict__ rp_tr,
                           const int* __restrict__ id_tt, const int* __restrict__ id_rt,
                           const int* __restrict__ id_tr,
                           float* __restrict__ is_tt, float* __restrict__ is_rt,
                           float* __restrict__ is_tr) {
  int i = blockIdx.x * blockDim.x + threadIdx.x;
  if (i >= N_TILE) return;
  int b = i >> 10;
  rp_tt[i] = pp_tt[i] + bs[0 * (NB + 1) + b];
  rp_rt[i] = pp_rt[i] + bs[1 * (NB + 1) + b];
  rp_tr[i] = pp_tr[i] + bs[2 * (NB + 1) + b];
  if (i == 0) {
    rp_tt[N_TILE] = bs[0 * (NB + 1) + NB];
    rp_rt[N_TILE] = bs[1 * (NB + 1) + NB];
    rp_tr[N_RR] = bs[2 * (NB + 1) + NB];
  }
  is_tt[i] = rsqrtf((float)max(id_tt[i], 1));
  is_rt[i] = rsqrtf((float)max(id_rt[i], 1));
  is_tr[i] = rsqrtf((float)max(id_tr[i], 1));
}

// ---------------- atomic-free CSR fill: writes (src, osc[src]) pairs ----------------
__global__ void k_fill_all(const int* __restrict__ tt_src, const int* __restrict__ tt_dst,
                           const int* __restrict__ rt_src, const int* __restrict__ rt_dst,
                           const int* __restrict__ tr_src, const int* __restrict__ tr_dst,
                           const int* __restrict__ rp_tt, const int* __restrict__ rp_rt,
                           const int* __restrict__ rp_tr,
                           const float* __restrict__ os_tt, const float* __restrict__ os_rt,
                           const float* __restrict__ os_tr,
                           const int* __restrict__ rank,
                           int2* __restrict__ pr_tt, int2* __restrict__ pr_rt,
                           int2* __restrict__ pr_tr) {
  int i = blockIdx.x * blockDim.x + threadIdx.x;
  if (i >= E_ALL) return;
  const int* src; const int* dst; const int* rp; const float* os; int2* pr; int j;
  if (i < E_TT) { j = i; src = tt_src; dst = tt_dst; rp = rp_tt; os = os_tt; pr = pr_tt; }
  else if (i < E_TT + E_RT) { j = i - E_TT; src = rt_src; dst = rt_dst; rp = rp_rt; os = os_rt; pr = pr_rt; }
  else { j = i - E_TT - E_RT; src = tr_src; dst = tr_dst; rp = rp_tr; os = os_tr; pr = pr_tr; }
  int d = dst[j];
  int s = src[j];
  int2 v;
  v.x = s;
  v.y = __float_as_int(os[s]);
  pr[rp[d] + rank[i]] = v;
}

// ---------------- fused aggregation: up to 3 relations, one wave per dst ----------------
// out[d] = isc[d] * sum_e w_e * x[src_e];  pairs pr[e] = (src_e, w_e)
// Half-wave layout: lanes 0-31 and 32-63 each load a full 512B row as float4
// -> one load instruction covers TWO edges. 4 rows in flight per half-wave.
__global__ __launch_bounds__(256) void k_agg3(
    const float* __restrict__ x0, const int* __restrict__ rp0, const int2* __restrict__ pr0,
    const float* __restrict__ isc0, float* __restrict__ out0, int n0,
    const float* __restrict__ x1, const int* __restrict__ rp1, const int2* __restrict__ pr1,
    const float* __restrict__ isc1, float* __restrict__ out1, int n1,
    const float* __restrict__ x2, const int* __restrict__ rp2, const int2* __restrict__ pr2,
    const float* __restrict__ isc2, float* __restrict__ out2, int n2) {
  int gw = (blockIdx.x * blockDim.x + threadIdx.x) >> 6;
  int lane = threadIdx.x & 63;
  int half = lane >> 5;      // which edge of the pair
  int l5 = lane & 31;        // float4 slot within the 128-float row
  const float* x; const int* rp; const int2* pr; const float* isc; float* out; int wid;
  if (gw < n0) { x = x0; rp = rp0; pr = pr0; isc = isc0; out = out0; wid = gw; }
  else if (gw < n0 + n1) { x = x1; rp = rp1; pr = pr1; isc = isc1; out = out1; wid = gw - n0; }
  else if (gw < n0 + n1 + n2) { x = x2; rp = rp2; pr = pr2; isc = isc2; out = out2; wid = gw - n0 - n1; }
  else return;
  int beg = rp[wid], end = rp[wid + 1];
  float4 a0 = make_float4(0.f, 0.f, 0.f, 0.f);
  float4 a1 = a0, a2 = a0, a3 = a0;
  const float4* xb = (const float4*)x + l5;
  for (int e = beg; e < end; e += 8) {
    int2 p0, p1, p2, p3;
    float w0, w1, w2, w3;
    {
      int i0 = e + 0 + half, i1 = e + 2 + half, i2 = e + 4 + half, i3 = e + 6 + half;
      int lim = end - 1;
      p0 = pr[min(i0, lim)];
      p1 = pr[min(i1, lim)];
      p2 = pr[min(i2, lim)];
      p3 = pr[min(i3, lim)];
      w0 = (i0 < end) ? __int_as_float(p0.y) : 0.f;
      w1 = (i1 < end) ? __int_as_float(p1.y) : 0.f;
      w2 = (i2 < end) ? __int_as_float(p2.y) : 0.f;
      w3 = (i3 < end) ? __int_as_float(p3.y) : 0.f;
    }
    float4 v0 = xb[(size_t)p0.x * 32];
    float4 v1 = xb[(size_t)p1.x * 32];
    float4 v2 = xb[(size_t)p2.x * 32];
    float4 v3 = xb[(size_t)p3.x * 32];
    a0.x = fmaf(v0.x, w0, a0.x); a0.y = fmaf(v0.y, w0, a0.y);
    a0.z = fmaf(v0.z, w0, a0.z); a0.w = fmaf(v0.w, w0, a0.w);
    a1.x = fmaf(v1.x, w1, a1.x); a1.y = fmaf(v1.y, w1, a1.y);
    a1.z = fmaf(v1.z, w1, a1.z); a1.w = fmaf(v1.w, w1, a1.w);
    a2.x = fmaf(v2.x, w2, a2.x); a2.y = fmaf(v2.y, w2, a2.y);
    a2.z = fmaf(v2.z, w2, a2.z); a2.w = fmaf(v2.w, w2, a2.w);
    a3.x = fmaf(v3.x, w3, a3.x); a3.y = fmaf(v3.y, w3, a3.y);
    a3.z = fmaf(v3.z, w3, a3.z); a3.w = fmaf(v3.w, w3, a3.w);
  }
  float4 s;
  s.x = (a0.x + a1.x) + (a2.x + a3.x);
  s.y = (a0.y + a1.y) + (a2.y + a3.y);
  s.z = (a0.z + a1.z) + (a2.z + a3.z);
  s.w = (a0.w + a1.w) + (a2.w + a3.w);
  // combine the two half-wave edge sets
  s.x += __shfl_xor(s.x, 32);
  s.y += __shfl_xor(s.y, 32);
  s.z += __shfl_xor(s.z, 32);
  s.w += __shfl_xor(s.w, 32);
  if (half == 0) {
    float iv = isc[wid];
    float4 r;
    r.x = s.x * iv; r.y = s.y * iv; r.z = s.z * iv; r.w = s.w * iv;
    ((float4*)(out + (size_t)wid * D))[l5] = r;
  }
}

// ---------------- fused GEMM(+GEMM) + bias + relu ----------------
// out[r][c] = relu( A[r,:]@W1[:,c] (+ B[r,:]@W2[:,c]) + b1[c] (+ b2[c]) )
#define GBM 64
#define GKC 32

template<bool TWO>
__global__ __launch_bounds__(256) void k_gemm(const float* __restrict__ A,
                                              const float* __restrict__ B,
                                              const float* __restrict__ W1,
                                              const float* __restrict__ W2,
                                              const float* __restrict__ b1,
                                              const float* __restrict__ b2,
                                              float* __restrict__ out, int nrows) {
  __shared__ float As[GBM][GKC + 1];
  __shared__ float Ws[GKC][132];
  int tid = threadIdx.x;
  int tx = tid & 15, ty = tid >> 4;
  int r0 = blockIdx.x * GBM;
  float acc[4][8];
#pragma unroll
  for (int i = 0; i < 4; ++i)
#pragma unroll
    for (int j = 0; j < 8; ++j) acc[i][j] = 0.f;

  const int nrel = TWO ? 2 : 1;
  for (int rel = 0; rel < nrel; ++rel) {
    const float* __restrict__ Xp = (rel == 0) ? A : B;
    const float* __restrict__ Wp = (rel == 0) ? W1 : W2;
    for (int k0 = 0; k0 < D; k0 += GKC) {
      {
        int lr = tid >> 3;
        int lk = (tid & 7) * 4;
#pragma unroll
        for (int h = 0; h < 2; ++h) {
          int rr = lr + h * 32;
          int gr = r0 + rr;
          float4 v = make_float4(0.f, 0.f, 0.f, 0.f);
          if (gr < nrows) v = *(const float4*)(Xp + (size_t)gr * D + k0 + lk);
          As[rr][lk] = v.x; As[rr][lk + 1] = v.y; As[rr][lk + 2] = v.z; As[rr][lk + 3] = v.w;
        }
        int wk = tid >> 5;
        int wc = (tid & 31) * 4;
#pragma unroll
        for (int h = 0; h < 4; ++h) {
          int kk = wk + h * 8;
          float4 v = *(const float4*)(Wp + (size_t)(k0 + kk) * D + wc);
          *(float4*)&Ws[kk][wc] = v;
        }
      }
      __syncthreads();
#pragma unroll 8
      for (int k = 0; k < GKC; ++k) {
        float a0 = As[ty * 4 + 0][k];
        float a1 = As[ty * 4 + 1][k];
        float a2 = As[ty * 4 + 2][k];
        float a3 = As[ty * 4 + 3][k];
        float4 bA = *(const float4*)&Ws[k][tx * 4];
        float4 bB = *(const float4*)&Ws[k][64 + tx * 4];
        acc[0][0] = fmaf(a0, bA.x, acc[0][0]); acc[0][1] = fmaf(a0, bA.y, acc[0][1]);
        acc[0][2] = fmaf(a0, bA.z, acc[0][2]); acc[0][3] = fmaf(a0, bA.w, acc[0][3]);
        acc[0][4] = fmaf(a0, bB.x, acc[0][4]); acc[0][5] = fmaf(a0, bB.y, acc[0][5]);
        acc[0][6] = fmaf(a0, bB.z, acc[0][6]); acc[0][7] = fmaf(a0, bB.w, acc[0][7]);
        acc[1][0] = fmaf(a1, bA.x, acc[1][0]); acc[1][1] = fmaf(a1, bA.y, acc[1][1]);
        acc[1][2] = fmaf(a1, bA.z, acc[1][2]); acc[1][3] = fmaf(a1, bA.w, acc[1][3]);
        acc[1][4] = fmaf(a1, bB.x, acc[1][4]); acc[1][5] = fmaf(a1, bB.y, acc[1][5]);
        acc[1][6] = fmaf(a1, bB.z, acc[1][6]); acc[1][7] = fmaf(a1, bB.w, acc[1][7]);
        acc[2][0] = fmaf(a2, bA.x, acc[2][0]); acc[2][1] = fmaf(a2, bA.y, acc[2][1]);
        acc[2][2] = fmaf(a2, bA.z, acc[2][2]); acc[2][3] = fmaf(a2, bA.w, acc[2][3]);
        acc[2][4] = fmaf(a2, bB.x, acc[2][4]); acc[2][5] = fmaf(a2, bB.y, acc[2][5]);
        acc[2][6] = fmaf(a2, bB.z, acc[2][6]); acc[2][7] = fmaf(a2, bB.w, acc[2][7]);
        acc[3][0] = fmaf(a3, bA.x, acc[3][0]); acc[3][1] = fmaf(a3, bA.y, acc[3][1]);
        acc[3][2] = fmaf(a3, bA.z, acc[3][2]); acc[3][3] = fmaf(a3, bA.w, acc[3][3]);
        acc[3][4] = fmaf(a3, bB.x, acc[3][4]); acc[3][5] = fmaf(a3, bB.y, acc[3][5]);
        acc[3][6] = fmaf(a3, bB.z, acc[3][6]); acc[3][7] = fmaf(a3, bB.w, acc[3][7]);
      }
      __syncthreads();
    }
  }

  float4 c0 = *(const float4*)&b1[tx * 4];
  float4 c1 = *(const float4*)&b1[64 + tx * 4];
  if constexpr (TWO) {
    float4 d0 = *(const float4*)&b2[tx * 4];
    float4 d1 = *(const float4*)&b2[64 + tx * 4];
    c0.x += d0.x; c0.y += d0.y; c0.z += d0.z; c0.w += d0.w;
    c1.x += d1.x; c1.y += d1.y; c1.z += d1.z; c1.w += d1.w;
  }
#pragma unroll
  for (int i = 0; i < 4; ++i) {
    int gr = r0 + ty * 4 + i;
    if (gr < nrows) {
      float4 o0, o1;
      o0.x = fmaxf(acc[i][0] + c0.x, 0.f);
      o0.y = fmaxf(acc[i][1] + c0.y, 0.f);
      o0.z = fmaxf(acc[i][2] + c0.z, 0.f);
      o0.w = fmaxf(acc[i][3] + c0.w, 0.f);
      o1.x = fmaxf(acc[i][4] + c1.x, 0.f);
      o1.y = fmaxf(acc[i][5] + c1.y, 0.f);
      o1.z = fmaxf(acc[i][6] + c1.z, 0.f);
      o1.w = fmaxf(acc[i][7] + c1.w, 0.f);
      *(float4*)(out + (size_t)gr * D + tx * 4) = o0;
      *(float4*)(out + (size_t)gr * D + 64 + tx * 4) = o1;
    }
  }
}

// ---------------- per-graph mean pooling (sorted gid -> segment partials) ----------------
#define PCHUNK 256
__global__ __launch_bounds__(128) void k_pool(const float* __restrict__ H,
                                              const int* __restrict__ gid,
                                              float* __restrict__ sums,
                                              float* __restrict__ cnt, int n) {
  int col = threadIdx.x;
  int start = blockIdx.x * PCHUNK;
  if (start >= n) return;
  int end = min(start + PCHUNK, n);
  float acc = 0.f;
  int cur = gid[start];
  int seglen = 0;
  for (int r = start; r < end; ++r) {
    int g = gid[r];
    if (g != cur) {
      atomicAdd(&sums[cur * D + col], acc);
      if (col == 0) atomicAdd(&cnt[cur], (float)seglen);
      acc = 0.f; seglen = 0; cur = g;
    }
    acc += H[(size_t)r * D + col];
    seglen++;
  }
  atomicAdd(&sums[cur * D + col], acc);
  if (col == 0) atomicAdd(&cnt[cur], (float)seglen);
}

// ---------------- final MLP on [16,128] ----------------
__global__ __launch_bounds__(256) void k_final(const float* __restrict__ sums,
                                               const float* __restrict__ cnt,
                                               const float* __restrict__ Wm1,
                                               const float* __restrict__ bm1,
                                               const float* __restrict__ Wm2,
                                               const float* __restrict__ bm2,
                                               float* __restrict__ out) {
  __shared__ float hg[16][128];
  __shared__ float t1[16][128];
  int tid = threadIdx.x;
  for (int i = tid; i < 16 * 128; i += 256) {
    int g = i >> 7, c = i & 127;
    hg[g][c] = sums[i] / fmaxf(cnt[g], 1.f);
  }
  __syncthreads();
  for (int i = tid; i < 16 * 128; i += 256) {
    int g = i >> 7, c = i & 127;
    float a = bm1[c];
    for (int k = 0; k < 128; ++k) a = fmaf(hg[g][k], Wm1[k * 128 + c], a);
    t1[g][c] = fmaxf(a, 0.f);
  }
  __syncthreads();
  int g = tid >> 4, l = tid & 15;
  float p = 0.f;
  for (int c = l; c < 128; c += 16) p = fmaf(t1[g][c], Wm2[c], p);
#pragma unroll
  for (int o = 8; o; o >>= 1) p += __shfl_down(p, o, 16);
  if (l == 0) out[g] = p + bm2[0];
}

extern "C" void kernel_launch(void* const* d_in, const int* in_sizes, int n_in,
                              void* d_out, int out_size, void* d_ws, size_t ws_size,
                              hipStream_t stream) {
  const float* x_tile = (const float*)d_in[0];
  const float* x_rr   = (const float*)d_in[1];
  const int* tt_src = (const int*)d_in[2];
  const int* tt_dst = (const int*)d_in[3];
  const int* rt_src = (const int*)d_in[4];
  const int* rt_dst = (const int*)d_in[5];
  const int* tr_src = (const int*)d_in[6];
  const int* tr_dst = (const int*)d_in[7];
  const int* tile_gid = (const int*)d_in[8];
  const float* W1_tt = (const float*)d_in[9];  const float* b1_tt = (const float*)d_in[10];
  const float* W1_rt = (const float*)d_in[11]; const float* b1_rt = (const float*)d_in[12];
  const float* W1_tr = (const float*)d_in[13]; const float* b1_tr = (const float*)d_in[14];
  const float* W2_tt = (const float*)d_in[15]; const float* b2_tt = (const float*)d_in[16];
  const float* W2_rt = (const float*)d_in[17]; const float* b2_rt = (const float*)d_in[18];
  const float* Wm1 = (const float*)d_in[21]; const float* bm1 = (const float*)d_in[22];
  const float* Wm2 = (const float*)d_in[23]; const float* bm2 = (const float*)d_in[24];

  char* ws = (char*)d_ws;
  size_t off = 0;
  auto alloc = [&](size_t elems) {
    void* p = ws + off;
    off += (elems * 4 + 255) & ~(size_t)255;
    return p;
  };
  // ---- zero region (memset each call) ----
  int* ideg_tt = (int*)alloc(N_TILE);
  int* ideg_rt = (int*)alloc(N_TILE);
  int* ideg_tr = (int*)alloc(N_RR);
  int* odc_tt = (int*)alloc((size_t)NCOPY * N_TILE);
  int* odc_rt = (int*)alloc((size_t)NCOPY * N_RR);
  int* odc_tr = (int*)alloc((size_t)NCOPY * N_TILE);
  float* psum = (float*)alloc(N_G * D);
  float* pcnt = (float*)alloc(N_G);
  size_t zero_bytes = off;
  // ---- rest ----
  int* rank = (int*)alloc(E_ALL);
  int* pp_tt = (int*)alloc(N_TILE);
  int* pp_rt = (int*)alloc(N_TILE);
  int* pp_tr = (int*)alloc(N_RR);
  int* bsum = (int*)alloc(3 * NB);
  int* bs = (int*)alloc(3 * (NB + 1));
  int* rp_tt = (int*)alloc(N_TILE + 1);
  int* rp_rt = (int*)alloc(N_TILE + 1);
  int* rp_tr = (int*)alloc(N_RR + 1);
  int2* pr_tt = (int2*)alloc((size_t)E_TT * 2);
  int2* pr_rt = (int2*)alloc((size_t)E_RT * 2);
  int2* pr_tr = (int2*)alloc((size_t)E_TR * 2);
  float* osc_tt = (float*)alloc(N_TILE);
  float* osc_rt = (float*)alloc(N_RR);
  float* osc_tr = (float*)alloc(N_TILE);
  float* isc_tt = (float*)alloc(N_TILE);
  float* isc_rt = (float*)alloc(N_TILE);
  float* isc_tr = (float*)alloc(N_RR);
  float* Abuf = (float*)alloc((size_t)N_TILE * D);
  float* Bbuf = (float*)alloc((size_t)N_TILE * D);
  float* Htile = (float*)alloc((size_t)N_TILE * D);
  float* Hrr = (float*)alloc((size_t)N_RR * D);
  (void)ws_size; (void)in_sizes; (void)n_in; (void)out_size;

  hipMemsetAsync(d_ws, 0, zero_bytes, stream);

  // ---- CSR build (edges identical for both layers -> build once) ----
  k_hist_all<<<(E_ALL + 255) / 256, 256, 0, stream>>>(
      tt_src, tt_dst, rt_src, rt_dst, tr_src, tr_dst,
      ideg_tt, ideg_rt, ideg_tr, odc_tt, odc_rt, odc_tr, rank);
  k_scan1<<<3 * NB, 1024, 0, stream>>>(ideg_tt, ideg_rt, ideg_tr, pp_tt, pp_rt, pp_tr, bsum,
                                       odc_tt, odc_rt, odc_tr, osc_tt, osc_rt, osc_tr);
  k_scan2<<<1, 256, 0, stream>>>(bsum, bs);
  k_finalize<<<(N_TILE + 255) / 256, 256, 0, stream>>>(
      pp_tt, pp_rt, pp_tr, bs, rp_tt, rp_rt, rp_tr,
      ideg_tt, ideg_rt, ideg_tr, isc_tt, isc_rt, isc_tr);
  k_fill_all<<<(E_ALL + 255) / 256, 256, 0, stream>>>(
      tt_src, tt_dst, rt_src, rt_dst, tr_src, tr_dst,
      rp_tt, rp_rt, rp_tr, osc_tt, osc_rt, osc_tr,
      rank, pr_tt, pr_rt, pr_tr);

  const int gemmBlocks = (N_TILE + GBM - 1) / GBM;

  // ---- layer 1: all three aggs fused (tr output parked in Htile) ----
  {
    int totw = N_TILE + N_TILE + N_RR;
    k_agg3<<<(totw * 64 + 255) / 256, 256, 0, stream>>>(
        x_tile, rp_tt, pr_tt, isc_tt, Abuf, N_TILE,
        x_rr,  rp_rt, pr_rt, isc_rt, Bbuf, N_TILE,
        x_tile, rp_tr, pr_tr, isc_tr, Htile, N_RR);
  }
  // tr GEMM first (consumes Htile before it is overwritten)
  k_gemm<false><<<gemmBlocks, 256, 0, stream>>>(Htile, nullptr, W1_tr, nullptr, b1_tr, nullptr, Hrr, N_RR);
  k_gemm<true><<<gemmBlocks, 256, 0, stream>>>(Abuf, Bbuf, W1_tt, W1_rt, b1_tt, b1_rt, Htile, N_TILE);

  // ---- layer 2 (h2_rr never consumed -> tr relation skipped) ----
  {
    int totw = N_TILE + N_TILE;
    k_agg3<<<(totw * 64 + 255) / 256, 256, 0, stream>>>(
        Htile, rp_tt, pr_tt, isc_tt, Abuf, N_TILE,
        Hrr,   rp_rt, pr_rt, isc_rt, Bbuf, N_TILE,
        nullptr, nullptr, nullptr, nullptr, nullptr, 0);
  }
  k_gemm<true><<<gemmBlocks, 256, 0, stream>>>(Abuf, Bbuf, W2_tt, W2_rt, b2_tt, b2_rt, Htile, N_TILE);

  // ---- pooling + MLP head ----
  k_pool<<<(N_TILE + PCHUNK - 1) / PCHUNK, 128, 0, stream>>>(Htile, tile_gid, psum, pcnt, N_TILE);
  k_final<<<1, 256, 0, stream>>>(psum, pcnt, Wm1, bm1, Wm2, bm2, (float*)d_out);
}